// Round 6
// baseline (432.908 us; speedup 1.0000x reference)
//
#include <hip/hip_runtime.h>
#include <math.h>

#define NEG_SLOPE 0.2f

typedef __attribute__((ext_vector_type(8))) short bfrag;   // 8 x bf16
typedef __attribute__((ext_vector_type(4))) float f32x4;

__device__ __forceinline__ float lrelu(float x) { return x > 0.f ? x : NEG_SLOPE * x; }

__device__ __forceinline__ unsigned short f2bf(float f) {
    union { float f; unsigned u; } v; v.f = f;
    unsigned r = v.u + 0x7fffu + ((v.u >> 16) & 1u);   // RNE
    return (unsigned short)(r >> 16);
}
__device__ __forceinline__ float bf2f_lo(unsigned p) { union { unsigned u; float f; } v; v.u = p << 16; return v.f; }
__device__ __forceinline__ float bf2f_hi(unsigned p) { union { unsigned u; float f; } v; v.u = p & 0xffff0000u; return v.f; }

// ---------------- prep: edge count (CSR) + all 3 W swizzles ----------------
__device__ __forceinline__ void wswz_body(const float* __restrict__ W, unsigned short* __restrict__ out,
                                          int DOUT, int tid) {
    int lane = tid & 63;
    int g = tid >> 6;
    int NT = DOUT >> 4;
    int tile = g % NT, kstep = g / NT;
    int q = lane >> 4, c = lane & 15;
    int n_ = tile * 16 + c;
    unsigned short v[8];
#pragma unroll
    for (int j = 0; j < 8; ++j) {
        int k = kstep * 32 + q * 8 + j;
        v[j] = f2bf(W[k * DOUT + n_]);
    }
    uint4 o;
    o.x = (unsigned)v[0] | ((unsigned)v[1] << 16);
    o.y = (unsigned)v[2] | ((unsigned)v[3] << 16);
    o.z = (unsigned)v[4] | ((unsigned)v[5] << 16);
    o.w = (unsigned)v[6] | ((unsigned)v[7] << 16);
    *(uint4*)(out + (size_t)tid * 8) = o;
}

__global__ void prep_kernel(const int* __restrict__ dst, int* __restrict__ counts, int E, int eb,
                            const float* __restrict__ W0, const float* __restrict__ W1,
                            const float* __restrict__ W2,
                            unsigned short* __restrict__ wz0, unsigned short* __restrict__ wz1,
                            unsigned short* __restrict__ wz2) {
    int b = blockIdx.x;
    if (b < eb) {
        int e = b * blockDim.x + threadIdx.x;
        if (e < E) atomicAdd(&counts[dst[e]], 1);
    } else {
        int wb = b - eb;                   // 0..19
        if (wb < 8)       wswz_body(W0, wz0, 128, wb * 256 + threadIdx.x);
        else if (wb < 16) wswz_body(W1, wz1, 128, (wb - 8) * 256 + threadIdx.x);
        else {
            int tid = (wb - 16) * 256 + threadIdx.x;
            if (tid < 1024) wswz_body(W2, wz2, 64, tid);
        }
    }
}

// ---------------- fused scan: one block, 1024 threads, CH seq elems each ----------------
__global__ __launch_bounds__(1024) void scan_all_kernel(const int* __restrict__ counts,
                                                        int* __restrict__ row_ptr,
                                                        int* __restrict__ cursor, int n, int E) {
    __shared__ int sm[1024];
    int tid = threadIdx.x;
    int CH = (n + 1023) >> 10;
    int base = tid * CH;
    int s = 0;
    for (int j = 0; j < CH; ++j) { int i = base + j; if (i < n) s += counts[i]; }
    int val = s; sm[tid] = val;
    for (int off = 1; off < 1024; off <<= 1) {
        __syncthreads();
        int t = (tid >= off) ? sm[tid - off] : 0;
        __syncthreads();
        val += t; sm[tid] = val;
    }
    int run = val - s;
    for (int j = 0; j < CH; ++j) {
        int i = base + j;
        if (i < n) { int c = counts[i]; row_ptr[i] = run; cursor[i] = run; run += c; }
    }
    if (tid == 0) row_ptr[n] = E;
}

// ---------------- GEMM body (bf16 MFMA) + attention dots, A from global ----------------
template<int DOUT, bool ABF>
__device__ __forceinline__ void gemm_body(
    int bid, const void* __restrict__ Xv, const unsigned short* __restrict__ Wswz,
    const float* __restrict__ avs, const float* __restrict__ avd,
    unsigned* __restrict__ Hout, float* __restrict__ as_out, float* __restrict__ ad_out,
    int n, float* __restrict__ smemw)
{
    constexpr int NT = DOUT / 16;
    int lane = threadIdx.x & 63;
    int w = threadIdx.x >> 6;
    int q = lane >> 4, c = lane & 15;
    int rowbase = bid * 64 + w * 16;
    int arow = rowbase + c;

    f32x4 acc[NT];
#pragma unroll
    for (int t = 0; t < NT; ++t) acc[t] = (f32x4){0.f, 0.f, 0.f, 0.f};

#pragma unroll
    for (int ks = 0; ks < 4; ++ks) {
        bfrag a = (bfrag)0;
        int k0 = ks * 32 + q * 8;
        if (ABF) {
            if (arow < n) a = *(const bfrag*)((const unsigned short*)Xv + (size_t)arow * 128 + k0);
        } else {
            if (arow < n) {
                const float* xp = (const float*)Xv + (size_t)arow * 128 + k0;
                float4 x0 = *(const float4*)xp, x1 = *(const float4*)(xp + 4);
                a[0] = (short)f2bf(x0.x); a[1] = (short)f2bf(x0.y);
                a[2] = (short)f2bf(x0.z); a[3] = (short)f2bf(x0.w);
                a[4] = (short)f2bf(x1.x); a[5] = (short)f2bf(x1.y);
                a[6] = (short)f2bf(x1.z); a[7] = (short)f2bf(x1.w);
            }
        }
#pragma unroll
        for (int t = 0; t < NT; ++t) {
            bfrag b = *(const bfrag*)(Wswz + ((size_t)(ks * NT + t) * 64 + lane) * 8);
            acc[t] = __builtin_amdgcn_mfma_f32_16x16x32_bf16(a, b, acc[t], 0, 0, 0);
        }
    }

    float* sm = smemw + w * (16 * 132);
#pragma unroll
    for (int t = 0; t < NT; ++t)
#pragma unroll
        for (int r = 0; r < 4; ++r)
            sm[(q * 4 + r) * 132 + t * 16 + c] = acc[t][r];
    __builtin_amdgcn_wave_barrier();

    if (DOUT == 128) {
#pragma unroll
        for (int it = 0; it < 4; ++it) {
            int r = it * 4 + q;
            int grow = rowbase + r;
            const float* rp = sm + r * 132 + c * 8;
            float4 xa = *(const float4*)rp, xb4 = *(const float4*)(rp + 4);
            uint4 o;
            o.x = (unsigned)f2bf(xa.x) | ((unsigned)f2bf(xa.y) << 16);
            o.y = (unsigned)f2bf(xa.z) | ((unsigned)f2bf(xa.w) << 16);
            o.z = (unsigned)f2bf(xb4.x) | ((unsigned)f2bf(xb4.y) << 16);
            o.w = (unsigned)f2bf(xb4.z) | ((unsigned)f2bf(xb4.w) << 16);
            if (grow < n) *(uint4*)(Hout + (size_t)grow * 64 + c * 4) = o;
        }
    } else {
#pragma unroll
        for (int it = 0; it < 4; ++it) {
            int r = it * 4 + q;
            int grow = rowbase + r;
            float4 v = *(const float4*)(sm + r * 132 + c * 4);
            uint2 o;
            o.x = (unsigned)f2bf(v.x) | ((unsigned)f2bf(v.y) << 16);
            o.y = (unsigned)f2bf(v.z) | ((unsigned)f2bf(v.w) << 16);
            if (grow < n) *(uint2*)(Hout + (size_t)grow * 32 + c * 2) = o;
        }
    }

    int dr = lane >> 2;
    int c0 = (lane & 3) * (DOUT / 4);
    float s = 0.f, d = 0.f;
#pragma unroll
    for (int j = 0; j < DOUT / 4; j += 4) {
        float4 hv = *(const float4*)(sm + dr * 132 + c0 + j);
        float4 av = *(const float4*)(avs + c0 + j);
        float4 dv = *(const float4*)(avd + c0 + j);
        s += hv.x * av.x + hv.y * av.y + hv.z * av.z + hv.w * av.w;
        d += hv.x * dv.x + hv.y * dv.y + hv.z * dv.z + hv.w * dv.w;
    }
    s += __shfl_down(s, 2); s += __shfl_down(s, 1);
    d += __shfl_down(d, 2); d += __shfl_down(d, 1);
    int grow = rowbase + dr;
    if ((lane & 3) == 0 && grow < n) { as_out[grow] = s; ad_out[grow] = d; }
}

// ---------------- layer-0 GEMM + CSR scatter in one launch ----------------
__global__ __launch_bounds__(256) void gemm0_scatter_kernel(
    const float* __restrict__ X, const unsigned short* __restrict__ Wswz,
    const float* __restrict__ avs, const float* __restrict__ avd,
    unsigned* __restrict__ Hout, float* __restrict__ as_out, float* __restrict__ ad_out,
    int n, int gemmb,
    const int* __restrict__ src, int* __restrict__ cursor,
    unsigned short* __restrict__ col, int E)
{
    __shared__ float smem[4 * 16 * 132];
    if (blockIdx.x >= gemmb) {
        int e = (blockIdx.x - gemmb) * blockDim.x + threadIdx.x;
        if (e < E) {
            int d = src[E + e];                       // dst half
            int pos = atomicAdd(&cursor[d], 1);
            col[pos] = (unsigned short)src[e];
        }
        return;
    }
    gemm_body<128, false>(blockIdx.x, X, Wswz, avs, avd, Hout, as_out, ad_out, n, smem);
}

// ---------------- fused aggregation + next-layer GEMM ----------------
// Phase A: 16-lane group per node, 4 nodes/group, 64 nodes/block. Each lane owns
// an 8-col slice of the 128-wide row -> no cross-lane accumulator reduction.
// Result (SiLU'd, bf16) goes to LDS in A-row-major; phase B runs MFMA GEMM + dots.
template<int DOUT>
__global__ __launch_bounds__(256) void agg_gemm_kernel(
    const unsigned* __restrict__ Hb,              // [n,128] bf16 packed, prev h
    const float* __restrict__ as_v, const float* __restrict__ ad_v,
    const float* __restrict__ bias,               // [128] prev bias
    const int* __restrict__ row_ptr, const unsigned short* __restrict__ col,
    const unsigned short* __restrict__ Wswz,      // next W swizzled
    const float* __restrict__ avs, const float* __restrict__ avd,
    unsigned* __restrict__ Hout, float* __restrict__ as_out, float* __restrict__ ad_out, int n)
{
    constexpr int NT = DOUT / 16;
    __shared__ unsigned short aLDS[64 * 136];     // 64 rows x 128 bf16, pitch 136
    __shared__ float smem[4 * 16 * 132];
    int tid = threadIdx.x;
    int gi = tid >> 4, il = tid & 15;

    // ---- phase A ----
    for (int sub = 0; sub < 4; ++sub) {
        int nl = gi * 4 + sub;
        int node = blockIdx.x * 64 + nl;
        uint4 o = {0u, 0u, 0u, 0u};
        if (node < n) {
            int beg = row_ptr[node], end = row_ptr[node + 1];
            float adv = ad_v[node];
            float c_self = __expf(fminf(lrelu(as_v[node] + adv), 60.f));
            uint4 hs = *(const uint4*)(Hb + (size_t)node * 64 + il * 4);
            float acc[8];
            acc[0] = c_self * bf2f_lo(hs.x); acc[1] = c_self * bf2f_hi(hs.x);
            acc[2] = c_self * bf2f_lo(hs.y); acc[3] = c_self * bf2f_hi(hs.y);
            acc[4] = c_self * bf2f_lo(hs.z); acc[5] = c_self * bf2f_hi(hs.z);
            acc[6] = c_self * bf2f_lo(hs.w); acc[7] = c_self * bf2f_hi(hs.w);
            float dpart = 0.f;
            for (int cb = beg; cb < end; cb += 16) {
                int idx = cb + il;
                int sreg = 0; float creg = 0.f;
                if (idx < end) {
                    sreg = col[idx];
                    creg = __expf(fminf(lrelu(as_v[sreg] + adv), 60.f));
                }
                dpart += creg;
                int cnt = end - cb; if (cnt > 16) cnt = 16;
                for (int k = 0; k < cnt; k += 2) {
                    int s0 = __shfl(sreg, k, 16);     float c0 = __shfl(creg, k, 16);
                    int s1 = __shfl(sreg, k + 1, 16); float c1 = __shfl(creg, k + 1, 16);
                    uint4 h0 = *(const uint4*)(Hb + (size_t)s0 * 64 + il * 4);
                    uint4 h1 = *(const uint4*)(Hb + (size_t)s1 * 64 + il * 4);
                    acc[0] += c0 * bf2f_lo(h0.x); acc[1] += c0 * bf2f_hi(h0.x);
                    acc[2] += c0 * bf2f_lo(h0.y); acc[3] += c0 * bf2f_hi(h0.y);
                    acc[4] += c0 * bf2f_lo(h0.z); acc[5] += c0 * bf2f_hi(h0.z);
                    acc[6] += c0 * bf2f_lo(h0.w); acc[7] += c0 * bf2f_hi(h0.w);
                    acc[0] += c1 * bf2f_lo(h1.x); acc[1] += c1 * bf2f_hi(h1.x);
                    acc[2] += c1 * bf2f_lo(h1.y); acc[3] += c1 * bf2f_hi(h1.y);
                    acc[4] += c1 * bf2f_lo(h1.z); acc[5] += c1 * bf2f_hi(h1.z);
                    acc[6] += c1 * bf2f_lo(h1.w); acc[7] += c1 * bf2f_hi(h1.w);
                }
            }
#pragma unroll
            for (int m = 1; m < 16; m <<= 1) dpart += __shfl_xor(dpart, m, 16);
            float inv = 1.f / (dpart + c_self);
            float4 b0v = *(const float4*)(bias + il * 8);
            float4 b1v = *(const float4*)(bias + il * 8 + 4);
            float v0 = acc[0] * inv + b0v.x, v1 = acc[1] * inv + b0v.y;
            float v2 = acc[2] * inv + b0v.z, v3 = acc[3] * inv + b0v.w;
            float v4 = acc[4] * inv + b1v.x, v5 = acc[5] * inv + b1v.y;
            float v6 = acc[6] * inv + b1v.z, v7 = acc[7] * inv + b1v.w;
            v0 /= (1.f + __expf(-v0)); v1 /= (1.f + __expf(-v1));
            v2 /= (1.f + __expf(-v2)); v3 /= (1.f + __expf(-v3));
            v4 /= (1.f + __expf(-v4)); v5 /= (1.f + __expf(-v5));
            v6 /= (1.f + __expf(-v6)); v7 /= (1.f + __expf(-v7));
            o.x = (unsigned)f2bf(v0) | ((unsigned)f2bf(v1) << 16);
            o.y = (unsigned)f2bf(v2) | ((unsigned)f2bf(v3) << 16);
            o.z = (unsigned)f2bf(v4) | ((unsigned)f2bf(v5) << 16);
            o.w = (unsigned)f2bf(v6) | ((unsigned)f2bf(v7) << 16);
        }
        *(uint4*)(&aLDS[nl * 136 + il * 8]) = o;
    }
    __syncthreads();

    // ---- phase B: GEMM from LDS A ----
    int lane = tid & 63;
    int w = tid >> 6;
    int q = lane >> 4, c = lane & 15;
    int rowbase = blockIdx.x * 64 + w * 16;

    f32x4 acc[NT];
#pragma unroll
    for (int t = 0; t < NT; ++t) acc[t] = (f32x4){0.f, 0.f, 0.f, 0.f};

#pragma unroll
    for (int ks = 0; ks < 4; ++ks) {
        bfrag a = *(const bfrag*)(&aLDS[(w * 16 + c) * 136 + ks * 32 + q * 8]);
#pragma unroll
        for (int t = 0; t < NT; ++t) {
            bfrag b = *(const bfrag*)(Wswz + ((size_t)(ks * NT + t) * 64 + lane) * 8);
            acc[t] = __builtin_amdgcn_mfma_f32_16x16x32_bf16(a, b, acc[t], 0, 0, 0);
        }
    }

    float* sm = smem + w * (16 * 132);
#pragma unroll
    for (int t = 0; t < NT; ++t)
#pragma unroll
        for (int r = 0; r < 4; ++r)
            sm[(q * 4 + r) * 132 + t * 16 + c] = acc[t][r];
    __builtin_amdgcn_wave_barrier();

    if (DOUT == 128) {
#pragma unroll
        for (int it = 0; it < 4; ++it) {
            int r = it * 4 + q;
            int grow = rowbase + r;
            const float* rp = sm + r * 132 + c * 8;
            float4 xa = *(const float4*)rp, xb4 = *(const float4*)(rp + 4);
            uint4 o;
            o.x = (unsigned)f2bf(xa.x) | ((unsigned)f2bf(xa.y) << 16);
            o.y = (unsigned)f2bf(xa.z) | ((unsigned)f2bf(xa.w) << 16);
            o.z = (unsigned)f2bf(xb4.x) | ((unsigned)f2bf(xb4.y) << 16);
            o.w = (unsigned)f2bf(xb4.z) | ((unsigned)f2bf(xb4.w) << 16);
            if (grow < n) *(uint4*)(Hout + (size_t)grow * 64 + c * 4) = o;
        }
    } else {
#pragma unroll
        for (int it = 0; it < 4; ++it) {
            int r = it * 4 + q;
            int grow = rowbase + r;
            float4 v = *(const float4*)(sm + r * 132 + c * 4);
            uint2 o;
            o.x = (unsigned)f2bf(v.x) | ((unsigned)f2bf(v.y) << 16);
            o.y = (unsigned)f2bf(v.z) | ((unsigned)f2bf(v.w) << 16);
            if (grow < n) *(uint2*)(Hout + (size_t)grow * 32 + c * 2) = o;
        }
    }

    int dr = lane >> 2;
    int c0 = (lane & 3) * (DOUT / 4);
    float s = 0.f, d = 0.f;
#pragma unroll
    for (int j = 0; j < DOUT / 4; j += 4) {
        float4 hv = *(const float4*)(sm + dr * 132 + c0 + j);
        float4 av = *(const float4*)(avs + c0 + j);
        float4 dv = *(const float4*)(avd + c0 + j);
        s += hv.x * av.x + hv.y * av.y + hv.z * av.z + hv.w * av.w;
        d += hv.x * dv.x + hv.y * dv.y + hv.z * dv.z + hv.w * dv.w;
    }
    s += __shfl_down(s, 2); s += __shfl_down(s, 1);
    d += __shfl_down(d, 2); d += __shfl_down(d, 1);
    int grow = rowbase + dr;
    if ((lane & 3) == 0 && grow < n) { as_out[grow] = s; ad_out[grow] = d; }
}

// ---------------- final aggregation: bf16 h [n,64], log_softmax, fp32 out ----------------
__global__ __launch_bounds__(256) void agg64_kernel(
    const unsigned* __restrict__ Hb, const float* __restrict__ as_v,
    const float* __restrict__ ad_v, const float* __restrict__ bias,
    const int* __restrict__ row_ptr, const unsigned short* __restrict__ col,
    float* __restrict__ out, int n)
{
    int tid = threadIdx.x;
    int gi = tid >> 4, il = tid & 15;
    int node = blockIdx.x * 16 + gi;
    if (node >= n) return;
    int beg = row_ptr[node], end = row_ptr[node + 1];
    float adv = ad_v[node];
    float c_self = __expf(fminf(lrelu(as_v[node] + adv), 60.f));

    uint2 hs = *(const uint2*)(Hb + (size_t)node * 32 + il * 2);
    float acc[4];
    acc[0] = c_self * bf2f_lo(hs.x); acc[1] = c_self * bf2f_hi(hs.x);
    acc[2] = c_self * bf2f_lo(hs.y); acc[3] = c_self * bf2f_hi(hs.y);
    float dpart = 0.f;

    for (int cb = beg; cb < end; cb += 16) {
        int idx = cb + il;
        int sreg = 0; float creg = 0.f;
        if (idx < end) {
            sreg = col[idx];
            creg = __expf(fminf(lrelu(as_v[sreg] + adv), 60.f));
        }
        dpart += creg;
        int cnt = end - cb; if (cnt > 16) cnt = 16;
        for (int k = 0; k < cnt; k += 2) {
            int s0 = __shfl(sreg, k, 16);     float c0 = __shfl(creg, k, 16);
            int s1 = __shfl(sreg, k + 1, 16); float c1 = __shfl(creg, k + 1, 16);
            uint2 h0 = *(const uint2*)(Hb + (size_t)s0 * 32 + il * 2);
            uint2 h1 = *(const uint2*)(Hb + (size_t)s1 * 32 + il * 2);
            acc[0] += c0 * bf2f_lo(h0.x); acc[1] += c0 * bf2f_hi(h0.x);
            acc[2] += c0 * bf2f_lo(h0.y); acc[3] += c0 * bf2f_hi(h0.y);
            acc[0] += c1 * bf2f_lo(h1.x); acc[1] += c1 * bf2f_hi(h1.x);
            acc[2] += c1 * bf2f_lo(h1.y); acc[3] += c1 * bf2f_hi(h1.y);
        }
    }

#pragma unroll
    for (int m = 1; m < 16; m <<= 1) dpart += __shfl_xor(dpart, m, 16);
    float inv = 1.f / (dpart + c_self);

    float4 bv = *(const float4*)(bias + il * 4);
    float v0 = acc[0] * inv + bv.x, v1 = acc[1] * inv + bv.y;
    float v2 = acc[2] * inv + bv.z, v3 = acc[3] * inv + bv.w;
    float mx = fmaxf(fmaxf(v0, v1), fmaxf(v2, v3));
#pragma unroll
    for (int m = 1; m < 16; m <<= 1) mx = fmaxf(mx, __shfl_xor(mx, m, 16));
    float sum = __expf(v0 - mx) + __expf(v1 - mx) + __expf(v2 - mx) + __expf(v3 - mx);
#pragma unroll
    for (int m = 1; m < 16; m <<= 1) sum += __shfl_xor(sum, m, 16);
    float ls = mx + logf(sum);
    float4 o = make_float4(v0 - ls, v1 - ls, v2 - ls, v3 - ls);
    *(float4*)(out + (size_t)node * 64 + il * 4) = o;
}

extern "C" void kernel_launch(void* const* d_in, const int* in_sizes, int n_in,
                              void* d_out, int out_size, void* d_ws, size_t ws_size,
                              hipStream_t stream) {
    const float* x   = (const float*)d_in[0];
    const int*   ei  = (const int*)d_in[1];
    const float* W0  = (const float*)d_in[2];
    const float* as0 = (const float*)d_in[3];
    const float* ad0 = (const float*)d_in[4];
    const float* b0  = (const float*)d_in[5];
    const float* W1  = (const float*)d_in[6];
    const float* as1 = (const float*)d_in[7];
    const float* ad1 = (const float*)d_in[8];
    const float* b1  = (const float*)d_in[9];
    const float* W2  = (const float*)d_in[10];
    const float* as2 = (const float*)d_in[11];
    const float* ad2 = (const float*)d_in[12];
    const float* b2  = (const float*)d_in[13];

    int n = in_sizes[0] / 128;
    int E = in_sizes[1] / 2;
    const int* dstv = ei + E;

    char* wsp = (char*)d_ws;
    auto alloc = [&](size_t bytes) {
        char* p = wsp;
        wsp += (bytes + 255) & ~(size_t)255;
        return p;
    };
    int*   counts  = (int*)alloc((size_t)n * 4);
    int*   row_ptr = (int*)alloc((size_t)(n + 1) * 4);
    int*   cursor  = (int*)alloc((size_t)n * 4);
    unsigned short* col = (unsigned short*)alloc((size_t)E * 2);
    unsigned short* wz0 = (unsigned short*)alloc(128 * 128 * 2);
    unsigned short* wz1 = (unsigned short*)alloc(128 * 128 * 2);
    unsigned short* wz2 = (unsigned short*)alloc(128 * 64 * 2);
    unsigned* hb0  = (unsigned*)alloc((size_t)n * 64 * 4);   // [n,128] bf16
    unsigned* hb1  = (unsigned*)alloc((size_t)n * 64 * 4);   // [n,128] bf16
    unsigned* hf   = (unsigned*)alloc((size_t)n * 32 * 4);   // [n,64]  bf16
    float*    asbA = (float*)alloc((size_t)n * 4);
    float*    adbA = (float*)alloc((size_t)n * 4);
    float*    asbB = (float*)alloc((size_t)n * 4);
    float*    adbB = (float*)alloc((size_t)n * 4);

    (void)hipMemsetAsync(counts, 0, (size_t)n * 4, stream);
    int eb = (E + 255) / 256;
    int gemmb = (n + 63) / 64;

    // CSR count + W swizzles
    prep_kernel<<<eb + 20, 256, 0, stream>>>(dstv, counts, E, eb, W0, W1, W2, wz0, wz1, wz2);
    // fused scan (row_ptr + cursor)
    scan_all_kernel<<<1, 1024, 0, stream>>>(counts, row_ptr, cursor, n, E);
    // layer-0 GEMM + dots, and CSR scatter, in one launch
    gemm0_scatter_kernel<<<gemmb + eb, 256, 0, stream>>>(x, wz0, as0, ad0, hb0, asbA, adbA,
                                                         n, gemmb, ei, cursor, col, E);
    // layer-0 agg + layer-1 GEMM + dots
    agg_gemm_kernel<128><<<gemmb, 256, 0, stream>>>(hb0, asbA, adbA, b0, row_ptr, col,
                                                    wz1, as1, ad1, hb1, asbB, adbB, n);
    // layer-1 agg + layer-2 GEMM + dots
    agg_gemm_kernel<64><<<gemmb, 256, 0, stream>>>(hb1, asbB, adbB, b1, row_ptr, col,
                                                   wz2, as2, ad2, hf, asbA, adbA, n);
    // final agg + log_softmax
    agg64_kernel<<<(n + 15) / 16, 256, 0, stream>>>(hf, asbA, adbA, b2, row_ptr, col,
                                                    (float*)d_out, n);
}

// Round 7
// 311.922 us; speedup vs baseline: 1.3879x; 1.3879x over previous
//
#include <hip/hip_runtime.h>
#include <math.h>

#define NEG_SLOPE 0.2f
constexpr int BS_SCAN = 1024;

typedef __attribute__((ext_vector_type(8))) short bfrag;   // 8 x bf16
typedef __attribute__((ext_vector_type(4))) float f32x4;

__device__ __forceinline__ float lrelu(float x) { return x > 0.f ? x : NEG_SLOPE * x; }

__device__ __forceinline__ unsigned short f2bf(float f) {
    union { float f; unsigned u; } v; v.f = f;
    unsigned r = v.u + 0x7fffu + ((v.u >> 16) & 1u);   // RNE
    return (unsigned short)(r >> 16);
}
__device__ __forceinline__ float bf2f_lo(unsigned p) { union { unsigned u; float f; } v; v.u = p << 16; return v.f; }
__device__ __forceinline__ float bf2f_hi(unsigned p) { union { unsigned u; float f; } v; v.u = p & 0xffff0000u; return v.f; }

// ---------------- prep: edge count (CSR) + all 3 W swizzles ----------------
__device__ __forceinline__ void wswz_body(const float* __restrict__ W, unsigned short* __restrict__ out,
                                          int DOUT, int tid) {
    int lane = tid & 63;
    int g = tid >> 6;
    int NT = DOUT >> 4;
    int tile = g % NT, kstep = g / NT;
    int q = lane >> 4, c = lane & 15;
    int n_ = tile * 16 + c;
    unsigned short v[8];
#pragma unroll
    for (int j = 0; j < 8; ++j) {
        int k = kstep * 32 + q * 8 + j;
        v[j] = f2bf(W[k * DOUT + n_]);
    }
    uint4 o;
    o.x = (unsigned)v[0] | ((unsigned)v[1] << 16);
    o.y = (unsigned)v[2] | ((unsigned)v[3] << 16);
    o.z = (unsigned)v[4] | ((unsigned)v[5] << 16);
    o.w = (unsigned)v[6] | ((unsigned)v[7] << 16);
    *(uint4*)(out + (size_t)tid * 8) = o;
}

__global__ void prep_kernel(const int* __restrict__ dst, int* __restrict__ counts, int E, int eb,
                            const float* __restrict__ W0, const float* __restrict__ W1,
                            const float* __restrict__ W2,
                            unsigned short* __restrict__ wz0, unsigned short* __restrict__ wz1,
                            unsigned short* __restrict__ wz2) {
    int b = blockIdx.x;
    if (b < eb) {
        int e = b * blockDim.x + threadIdx.x;
        if (e < E) atomicAdd(&counts[dst[e]], 1);
    } else {
        int wb = b - eb;                   // 0..19
        if (wb < 8)       wswz_body(W0, wz0, 128, wb * 256 + threadIdx.x);
        else if (wb < 16) wswz_body(W1, wz1, 128, (wb - 8) * 256 + threadIdx.x);
        else {
            int tid = (wb - 16) * 256 + threadIdx.x;
            if (tid < 1024) wswz_body(W2, wz2, 64, tid);
        }
    }
}

// ---------------- scan phase 1: per-block exclusive scan of counts ----------------
__global__ __launch_bounds__(1024) void scan1_kernel(const int* __restrict__ counts,
                                                     int* __restrict__ excl,
                                                     int* __restrict__ totals, int n) {
    __shared__ int sm[BS_SCAN];
    int tid = threadIdx.x;
    int i = blockIdx.x * BS_SCAN + tid;
    int v = (i < n) ? counts[i] : 0;
    int val = v;
    sm[tid] = val;
    for (int off = 1; off < BS_SCAN; off <<= 1) {
        __syncthreads();
        int t = (tid >= off) ? sm[tid - off] : 0;
        __syncthreads();
        val += t; sm[tid] = val;
    }
    if (i < n) excl[i] = val - v;
    if (tid == BS_SCAN - 1) totals[blockIdx.x] = val;
}

// ---------------- scan phase 2+3: add block offset (redundant wave-reduce, nb<=64) ----------------
__global__ __launch_bounds__(1024) void scan23_kernel(int* __restrict__ row_ptr,
                                                      const int* __restrict__ totals,
                                                      int* __restrict__ cursor, int n, int E, int nb) {
    __shared__ int s_off;
    int tid = threadIdx.x;
    if (tid < 64) {
        int v = (tid < blockIdx.x && tid < nb) ? totals[tid] : 0;
#pragma unroll
        for (int off = 32; off; off >>= 1) v += __shfl_xor(v, off);
        if (tid == 0) s_off = v;
    }
    __syncthreads();
    int off = s_off;
    int i = blockIdx.x * BS_SCAN + tid;
    if (i < n) {
        int rp = row_ptr[i] + off;
        row_ptr[i] = rp;
        cursor[i] = rp;
    }
    if (i == 0) row_ptr[n] = E;
}

// ---------------- GEMM body (bf16 MFMA) + attention dots, A from global ----------------
template<int DOUT, bool ABF>
__device__ __forceinline__ void gemm_body(
    int bid, const void* __restrict__ Xv, const unsigned short* __restrict__ Wswz,
    const float* __restrict__ avs, const float* __restrict__ avd,
    unsigned* __restrict__ Hout, float* __restrict__ as_out, float* __restrict__ ad_out,
    int n, float* __restrict__ smemw)
{
    constexpr int NT = DOUT / 16;
    int lane = threadIdx.x & 63;
    int w = threadIdx.x >> 6;
    int q = lane >> 4, c = lane & 15;
    int rowbase = bid * 64 + w * 16;
    int arow = rowbase + c;

    f32x4 acc[NT];
#pragma unroll
    for (int t = 0; t < NT; ++t) acc[t] = (f32x4){0.f, 0.f, 0.f, 0.f};

#pragma unroll
    for (int ks = 0; ks < 4; ++ks) {
        bfrag a = (bfrag)0;
        int k0 = ks * 32 + q * 8;
        if (ABF) {
            if (arow < n) a = *(const bfrag*)((const unsigned short*)Xv + (size_t)arow * 128 + k0);
        } else {
            if (arow < n) {
                const float* xp = (const float*)Xv + (size_t)arow * 128 + k0;
                float4 x0 = *(const float4*)xp, x1 = *(const float4*)(xp + 4);
                a[0] = (short)f2bf(x0.x); a[1] = (short)f2bf(x0.y);
                a[2] = (short)f2bf(x0.z); a[3] = (short)f2bf(x0.w);
                a[4] = (short)f2bf(x1.x); a[5] = (short)f2bf(x1.y);
                a[6] = (short)f2bf(x1.z); a[7] = (short)f2bf(x1.w);
            }
        }
#pragma unroll
        for (int t = 0; t < NT; ++t) {
            bfrag b = *(const bfrag*)(Wswz + ((size_t)(ks * NT + t) * 64 + lane) * 8);
            acc[t] = __builtin_amdgcn_mfma_f32_16x16x32_bf16(a, b, acc[t], 0, 0, 0);
        }
    }

    float* sm = smemw + w * (16 * 132);
#pragma unroll
    for (int t = 0; t < NT; ++t)
#pragma unroll
        for (int r = 0; r < 4; ++r)
            sm[(q * 4 + r) * 132 + t * 16 + c] = acc[t][r];
    __builtin_amdgcn_wave_barrier();

    if (DOUT == 128) {
#pragma unroll
        for (int it = 0; it < 4; ++it) {
            int r = it * 4 + q;
            int grow = rowbase + r;
            const float* rp = sm + r * 132 + c * 8;
            float4 xa = *(const float4*)rp, xb4 = *(const float4*)(rp + 4);
            uint4 o;
            o.x = (unsigned)f2bf(xa.x) | ((unsigned)f2bf(xa.y) << 16);
            o.y = (unsigned)f2bf(xa.z) | ((unsigned)f2bf(xa.w) << 16);
            o.z = (unsigned)f2bf(xb4.x) | ((unsigned)f2bf(xb4.y) << 16);
            o.w = (unsigned)f2bf(xb4.z) | ((unsigned)f2bf(xb4.w) << 16);
            if (grow < n) *(uint4*)(Hout + (size_t)grow * 64 + c * 4) = o;
        }
    } else {
#pragma unroll
        for (int it = 0; it < 4; ++it) {
            int r = it * 4 + q;
            int grow = rowbase + r;
            float4 v = *(const float4*)(sm + r * 132 + c * 4);
            uint2 o;
            o.x = (unsigned)f2bf(v.x) | ((unsigned)f2bf(v.y) << 16);
            o.y = (unsigned)f2bf(v.z) | ((unsigned)f2bf(v.w) << 16);
            if (grow < n) *(uint2*)(Hout + (size_t)grow * 32 + c * 2) = o;
        }
    }

    int dr = lane >> 2;
    int c0 = (lane & 3) * (DOUT / 4);
    float s = 0.f, d = 0.f;
#pragma unroll
    for (int j = 0; j < DOUT / 4; j += 4) {
        float4 hv = *(const float4*)(sm + dr * 132 + c0 + j);
        float4 av = *(const float4*)(avs + c0 + j);
        float4 dv = *(const float4*)(avd + c0 + j);
        s += hv.x * av.x + hv.y * av.y + hv.z * av.z + hv.w * av.w;
        d += hv.x * dv.x + hv.y * dv.y + hv.z * dv.z + hv.w * dv.w;
    }
    s += __shfl_down(s, 2); s += __shfl_down(s, 1);
    d += __shfl_down(d, 2); d += __shfl_down(d, 1);
    int grow = rowbase + dr;
    if ((lane & 3) == 0 && grow < n) { as_out[grow] = s; ad_out[grow] = d; }
}

// ---------------- layer-0 GEMM + CSR scatter in one launch ----------------
__global__ __launch_bounds__(256) void gemm0_scatter_kernel(
    const float* __restrict__ X, const unsigned short* __restrict__ Wswz,
    const float* __restrict__ avs, const float* __restrict__ avd,
    unsigned* __restrict__ Hout, float* __restrict__ as_out, float* __restrict__ ad_out,
    int n, int gemmb,
    const int* __restrict__ src, int* __restrict__ cursor,
    unsigned short* __restrict__ col, int E)
{
    __shared__ float smem[4 * 16 * 132];
    if (blockIdx.x >= gemmb) {
        int e = (blockIdx.x - gemmb) * blockDim.x + threadIdx.x;
        if (e < E) {
            int d = src[E + e];                       // dst half
            int pos = atomicAdd(&cursor[d], 1);
            col[pos] = (unsigned short)src[e];
        }
        return;
    }
    gemm_body<128, false>(blockIdx.x, X, Wswz, avs, avd, Hout, as_out, ad_out, n, smem);
}

// ---------------- fused aggregation + next-layer GEMM ----------------
template<int DOUT>
__global__ __launch_bounds__(256) void agg_gemm_kernel(
    const unsigned* __restrict__ Hb,              // [n,128] bf16 packed, prev h
    const float* __restrict__ as_v, const float* __restrict__ ad_v,
    const float* __restrict__ bias,               // [128] prev bias
    const int* __restrict__ row_ptr, const unsigned short* __restrict__ col,
    const unsigned short* __restrict__ Wswz,      // next W swizzled
    const float* __restrict__ avs, const float* __restrict__ avd,
    unsigned* __restrict__ Hout, float* __restrict__ as_out, float* __restrict__ ad_out, int n)
{
    constexpr int NT = DOUT / 16;
    __shared__ unsigned short aLDS[64 * 136];     // 64 rows x 128 bf16, pitch 136
    __shared__ float smem[4 * 16 * 132];
    int tid = threadIdx.x;
    int gi = tid >> 4, il = tid & 15;

    // ---- phase A: aggregate 64 nodes, SiLU, write bf16 rows to LDS ----
    for (int sub = 0; sub < 4; ++sub) {
        int nl = gi * 4 + sub;
        int node = blockIdx.x * 64 + nl;
        uint4 o = {0u, 0u, 0u, 0u};
        if (node < n) {
            int beg = row_ptr[node], end = row_ptr[node + 1];
            float adv = ad_v[node];
            float c_self = __expf(fminf(lrelu(as_v[node] + adv), 60.f));
            uint4 hs = *(const uint4*)(Hb + (size_t)node * 64 + il * 4);
            float acc[8];
            acc[0] = c_self * bf2f_lo(hs.x); acc[1] = c_self * bf2f_hi(hs.x);
            acc[2] = c_self * bf2f_lo(hs.y); acc[3] = c_self * bf2f_hi(hs.y);
            acc[4] = c_self * bf2f_lo(hs.z); acc[5] = c_self * bf2f_hi(hs.z);
            acc[6] = c_self * bf2f_lo(hs.w); acc[7] = c_self * bf2f_hi(hs.w);
            float dpart = 0.f;
            for (int cb = beg; cb < end; cb += 16) {
                int idx = cb + il;
                int sreg = 0; float creg = 0.f;
                if (idx < end) {
                    sreg = col[idx];
                    creg = __expf(fminf(lrelu(as_v[sreg] + adv), 60.f));
                }
                dpart += creg;
                int cnt = end - cb; if (cnt > 16) cnt = 16;
                for (int k = 0; k < cnt; k += 2) {
                    int s0 = __shfl(sreg, k, 16);     float c0 = __shfl(creg, k, 16);
                    int s1 = __shfl(sreg, k + 1, 16); float c1 = __shfl(creg, k + 1, 16);
                    uint4 h0 = *(const uint4*)(Hb + (size_t)s0 * 64 + il * 4);
                    uint4 h1 = *(const uint4*)(Hb + (size_t)s1 * 64 + il * 4);
                    acc[0] += c0 * bf2f_lo(h0.x); acc[1] += c0 * bf2f_hi(h0.x);
                    acc[2] += c0 * bf2f_lo(h0.y); acc[3] += c0 * bf2f_hi(h0.y);
                    acc[4] += c0 * bf2f_lo(h0.z); acc[5] += c0 * bf2f_hi(h0.z);
                    acc[6] += c0 * bf2f_lo(h0.w); acc[7] += c0 * bf2f_hi(h0.w);
                    acc[0] += c1 * bf2f_lo(h1.x); acc[1] += c1 * bf2f_hi(h1.x);
                    acc[2] += c1 * bf2f_lo(h1.y); acc[3] += c1 * bf2f_hi(h1.y);
                    acc[4] += c1 * bf2f_lo(h1.z); acc[5] += c1 * bf2f_hi(h1.z);
                    acc[6] += c1 * bf2f_lo(h1.w); acc[7] += c1 * bf2f_hi(h1.w);
                }
            }
#pragma unroll
            for (int m = 1; m < 16; m <<= 1) dpart += __shfl_xor(dpart, m, 16);
            float inv = 1.f / (dpart + c_self);
            float4 b0v = *(const float4*)(bias + il * 8);
            float4 b1v = *(const float4*)(bias + il * 8 + 4);
            float v0 = acc[0] * inv + b0v.x, v1 = acc[1] * inv + b0v.y;
            float v2 = acc[2] * inv + b0v.z, v3 = acc[3] * inv + b0v.w;
            float v4 = acc[4] * inv + b1v.x, v5 = acc[5] * inv + b1v.y;
            float v6 = acc[6] * inv + b1v.z, v7 = acc[7] * inv + b1v.w;
            v0 /= (1.f + __expf(-v0)); v1 /= (1.f + __expf(-v1));
            v2 /= (1.f + __expf(-v2)); v3 /= (1.f + __expf(-v3));
            v4 /= (1.f + __expf(-v4)); v5 /= (1.f + __expf(-v5));
            v6 /= (1.f + __expf(-v6)); v7 /= (1.f + __expf(-v7));
            o.x = (unsigned)f2bf(v0) | ((unsigned)f2bf(v1) << 16);
            o.y = (unsigned)f2bf(v2) | ((unsigned)f2bf(v3) << 16);
            o.z = (unsigned)f2bf(v4) | ((unsigned)f2bf(v5) << 16);
            o.w = (unsigned)f2bf(v6) | ((unsigned)f2bf(v7) << 16);
        }
        *(uint4*)(&aLDS[nl * 136 + il * 8]) = o;
    }
    __syncthreads();

    // ---- phase B: GEMM from LDS A ----
    int lane = tid & 63;
    int w = tid >> 6;
    int q = lane >> 4, c = lane & 15;
    int rowbase = blockIdx.x * 64 + w * 16;

    f32x4 acc[NT];
#pragma unroll
    for (int t = 0; t < NT; ++t) acc[t] = (f32x4){0.f, 0.f, 0.f, 0.f};

#pragma unroll
    for (int ks = 0; ks < 4; ++ks) {
        bfrag a = *(const bfrag*)(&aLDS[(w * 16 + c) * 136 + ks * 32 + q * 8]);
#pragma unroll
        for (int t = 0; t < NT; ++t) {
            bfrag b = *(const bfrag*)(Wswz + ((size_t)(ks * NT + t) * 64 + lane) * 8);
            acc[t] = __builtin_amdgcn_mfma_f32_16x16x32_bf16(a, b, acc[t], 0, 0, 0);
        }
    }

    float* sm = smem + w * (16 * 132);
#pragma unroll
    for (int t = 0; t < NT; ++t)
#pragma unroll
        for (int r = 0; r < 4; ++r)
            sm[(q * 4 + r) * 132 + t * 16 + c] = acc[t][r];
    __builtin_amdgcn_wave_barrier();

    if (DOUT == 128) {
#pragma unroll
        for (int it = 0; it < 4; ++it) {
            int r = it * 4 + q;
            int grow = rowbase + r;
            const float* rp = sm + r * 132 + c * 8;
            float4 xa = *(const float4*)rp, xb4 = *(const float4*)(rp + 4);
            uint4 o;
            o.x = (unsigned)f2bf(xa.x) | ((unsigned)f2bf(xa.y) << 16);
            o.y = (unsigned)f2bf(xa.z) | ((unsigned)f2bf(xa.w) << 16);
            o.z = (unsigned)f2bf(xb4.x) | ((unsigned)f2bf(xb4.y) << 16);
            o.w = (unsigned)f2bf(xb4.z) | ((unsigned)f2bf(xb4.w) << 16);
            if (grow < n) *(uint4*)(Hout + (size_t)grow * 64 + c * 4) = o;
        }
    } else {
#pragma unroll
        for (int it = 0; it < 4; ++it) {
            int r = it * 4 + q;
            int grow = rowbase + r;
            float4 v = *(const float4*)(sm + r * 132 + c * 4);
            uint2 o;
            o.x = (unsigned)f2bf(v.x) | ((unsigned)f2bf(v.y) << 16);
            o.y = (unsigned)f2bf(v.z) | ((unsigned)f2bf(v.w) << 16);
            if (grow < n) *(uint2*)(Hout + (size_t)grow * 32 + c * 2) = o;
        }
    }

    int dr = lane >> 2;
    int c0 = (lane & 3) * (DOUT / 4);
    float s = 0.f, d = 0.f;
#pragma unroll
    for (int j = 0; j < DOUT / 4; j += 4) {
        float4 hv = *(const float4*)(sm + dr * 132 + c0 + j);
        float4 av = *(const float4*)(avs + c0 + j);
        float4 dv = *(const float4*)(avd + c0 + j);
        s += hv.x * av.x + hv.y * av.y + hv.z * av.z + hv.w * av.w;
        d += hv.x * dv.x + hv.y * dv.y + hv.z * dv.z + hv.w * dv.w;
    }
    s += __shfl_down(s, 2); s += __shfl_down(s, 1);
    d += __shfl_down(d, 2); d += __shfl_down(d, 1);
    int grow = rowbase + dr;
    if ((lane & 3) == 0 && grow < n) { as_out[grow] = s; ad_out[grow] = d; }
}

// ---------------- final aggregation: bf16 h [n,64], log_softmax, fp32 out ----------------
__global__ __launch_bounds__(256) void agg64_kernel(
    const unsigned* __restrict__ Hb, const float* __restrict__ as_v,
    const float* __restrict__ ad_v, const float* __restrict__ bias,
    const int* __restrict__ row_ptr, const unsigned short* __restrict__ col,
    float* __restrict__ out, int n)
{
    int tid = threadIdx.x;
    int gi = tid >> 4, il = tid & 15;
    int node = blockIdx.x * 16 + gi;
    if (node >= n) return;
    int beg = row_ptr[node], end = row_ptr[node + 1];
    float adv = ad_v[node];
    float c_self = __expf(fminf(lrelu(as_v[node] + adv), 60.f));

    uint2 hs = *(const uint2*)(Hb + (size_t)node * 32 + il * 2);
    float acc[4];
    acc[0] = c_self * bf2f_lo(hs.x); acc[1] = c_self * bf2f_hi(hs.x);
    acc[2] = c_self * bf2f_lo(hs.y); acc[3] = c_self * bf2f_hi(hs.y);
    float dpart = 0.f;

    for (int cb = beg; cb < end; cb += 16) {
        int idx = cb + il;
        int sreg = 0; float creg = 0.f;
        if (idx < end) {
            sreg = col[idx];
            creg = __expf(fminf(lrelu(as_v[sreg] + adv), 60.f));
        }
        dpart += creg;
        int cnt = end - cb; if (cnt > 16) cnt = 16;
        for (int k = 0; k < cnt; k += 2) {
            int s0 = __shfl(sreg, k, 16);     float c0 = __shfl(creg, k, 16);
            int s1 = __shfl(sreg, k + 1, 16); float c1 = __shfl(creg, k + 1, 16);
            uint2 h0 = *(const uint2*)(Hb + (size_t)s0 * 32 + il * 2);
            uint2 h1 = *(const uint2*)(Hb + (size_t)s1 * 32 + il * 2);
            acc[0] += c0 * bf2f_lo(h0.x); acc[1] += c0 * bf2f_hi(h0.x);
            acc[2] += c0 * bf2f_lo(h0.y); acc[3] += c0 * bf2f_hi(h0.y);
            acc[0] += c1 * bf2f_lo(h1.x); acc[1] += c1 * bf2f_hi(h1.x);
            acc[2] += c1 * bf2f_lo(h1.y); acc[3] += c1 * bf2f_hi(h1.y);
        }
    }

#pragma unroll
    for (int m = 1; m < 16; m <<= 1) dpart += __shfl_xor(dpart, m, 16);
    float inv = 1.f / (dpart + c_self);

    float4 bv = *(const float4*)(bias + il * 4);
    float v0 = acc[0] * inv + bv.x, v1 = acc[1] * inv + bv.y;
    float v2 = acc[2] * inv + bv.z, v3 = acc[3] * inv + bv.w;
    float mx = fmaxf(fmaxf(v0, v1), fmaxf(v2, v3));
#pragma unroll
    for (int m = 1; m < 16; m <<= 1) mx = fmaxf(mx, __shfl_xor(mx, m, 16));
    float sum = __expf(v0 - mx) + __expf(v1 - mx) + __expf(v2 - mx) + __expf(v3 - mx);
#pragma unroll
    for (int m = 1; m < 16; m <<= 1) sum += __shfl_xor(sum, m, 16);
    float ls = mx + logf(sum);
    float4 o = make_float4(v0 - ls, v1 - ls, v2 - ls, v3 - ls);
    *(float4*)(out + (size_t)node * 64 + il * 4) = o;
}

extern "C" void kernel_launch(void* const* d_in, const int* in_sizes, int n_in,
                              void* d_out, int out_size, void* d_ws, size_t ws_size,
                              hipStream_t stream) {
    const float* x   = (const float*)d_in[0];
    const int*   ei  = (const int*)d_in[1];
    const float* W0  = (const float*)d_in[2];
    const float* as0 = (const float*)d_in[3];
    const float* ad0 = (const float*)d_in[4];
    const float* b0  = (const float*)d_in[5];
    const float* W1  = (const float*)d_in[6];
    const float* as1 = (const float*)d_in[7];
    const float* ad1 = (const float*)d_in[8];
    const float* b1  = (const float*)d_in[9];
    const float* W2  = (const float*)d_in[10];
    const float* as2 = (const float*)d_in[11];
    const float* ad2 = (const float*)d_in[12];
    const float* b2  = (const float*)d_in[13];

    int n = in_sizes[0] / 128;
    int E = in_sizes[1] / 2;
    const int* dstv = ei + E;

    char* wsp = (char*)d_ws;
    auto alloc = [&](size_t bytes) {
        char* p = wsp;
        wsp += (bytes + 255) & ~(size_t)255;
        return p;
    };
    int*   counts  = (int*)alloc((size_t)n * 4);
    int*   row_ptr = (int*)alloc((size_t)(n + 1) * 4);
    int*   cursor  = (int*)alloc((size_t)n * 4);
    int*   totals  = (int*)alloc(256 * 4);
    unsigned short* col = (unsigned short*)alloc((size_t)E * 2);
    unsigned short* wz0 = (unsigned short*)alloc(128 * 128 * 2);
    unsigned short* wz1 = (unsigned short*)alloc(128 * 128 * 2);
    unsigned short* wz2 = (unsigned short*)alloc(128 * 64 * 2);
    unsigned* hb0  = (unsigned*)alloc((size_t)n * 64 * 4);   // [n,128] bf16
    unsigned* hb1  = (unsigned*)alloc((size_t)n * 64 * 4);   // [n,128] bf16
    unsigned* hf   = (unsigned*)alloc((size_t)n * 32 * 4);   // [n,64]  bf16
    float*    asbA = (float*)alloc((size_t)n * 4);
    float*    adbA = (float*)alloc((size_t)n * 4);
    float*    asbB = (float*)alloc((size_t)n * 4);
    float*    adbB = (float*)alloc((size_t)n * 4);

    (void)hipMemsetAsync(counts, 0, (size_t)n * 4, stream);
    int eb = (E + 255) / 256;
    int gemmb = (n + 63) / 64;
    int nb = (n + BS_SCAN - 1) / BS_SCAN;   // 49 <= 64 (scan23 wave-reduce bound)

    // CSR count + W swizzles
    prep_kernel<<<eb + 20, 256, 0, stream>>>(dstv, counts, E, eb, W0, W1, W2, wz0, wz1, wz2);
    // two-phase scan (multi-block; R6's single-block scan was a 128 us serialization bug)
    scan1_kernel<<<nb, BS_SCAN, 0, stream>>>(counts, row_ptr, totals, n);
    scan23_kernel<<<nb, BS_SCAN, 0, stream>>>(row_ptr, totals, cursor, n, E, nb);
    // layer-0 GEMM + dots, and CSR scatter, in one launch
    gemm0_scatter_kernel<<<gemmb + eb, 256, 0, stream>>>(x, wz0, as0, ad0, hb0, asbA, adbA,
                                                         n, gemmb, ei, cursor, col, E);
    // layer-0 agg + layer-1 GEMM + dots
    agg_gemm_kernel<128><<<gemmb, 256, 0, stream>>>(hb0, asbA, adbA, b0, row_ptr, col,
                                                    wz1, as1, ad1, hb1, asbB, adbB, n);
    // layer-1 agg + layer-2 GEMM + dots
    agg_gemm_kernel<64><<<gemmb, 256, 0, stream>>>(hb1, asbB, adbB, b1, row_ptr, col,
                                                   wz2, as2, ad2, hf, asbA, adbA, n);
    // final agg + log_softmax
    agg64_kernel<<<(n + 15) / 16, 256, 0, stream>>>(hf, asbA, adbA, b2, row_ptr, col,
                                                    (float*)d_out, n);
}

// Round 8
// 299.828 us; speedup vs baseline: 1.4439x; 1.0403x over previous
//
#include <hip/hip_runtime.h>
#include <math.h>

#define NEG_SLOPE 0.2f
constexpr int BS_SCAN = 1024;
constexpr int TILE_SHIFT = 13;          // 8192 rows/tile: 2 MB bf16x128 rows <= L2/2
constexpr int NTILE = 8;                // supports n <= 65536

typedef __attribute__((ext_vector_type(8))) short bfrag;   // 8 x bf16
typedef __attribute__((ext_vector_type(4))) float f32x4;

__device__ __forceinline__ float lrelu(float x) { return x > 0.f ? x : NEG_SLOPE * x; }

__device__ __forceinline__ unsigned short f2bf(float f) {
    union { float f; unsigned u; } v; v.f = f;
    unsigned r = v.u + 0x7fffu + ((v.u >> 16) & 1u);   // RNE
    return (unsigned short)(r >> 16);
}
__device__ __forceinline__ float bf2f_lo(unsigned p) { union { unsigned u; float f; } v; v.u = p << 16; return v.f; }
__device__ __forceinline__ float bf2f_hi(unsigned p) { union { unsigned u; float f; } v; v.u = p & 0xffff0000u; return v.f; }

// ---------------- prep: per-(dst,tile) edge count + all 3 W swizzles ----------------
__device__ __forceinline__ void wswz_body(const float* __restrict__ W, unsigned short* __restrict__ out,
                                          int DOUT, int tid) {
    int lane = tid & 63;
    int g = tid >> 6;
    int NT = DOUT >> 4;
    int tile = g % NT, kstep = g / NT;
    int q = lane >> 4, c = lane & 15;
    int n_ = tile * 16 + c;
    unsigned short v[8];
#pragma unroll
    for (int j = 0; j < 8; ++j) {
        int k = kstep * 32 + q * 8 + j;
        v[j] = f2bf(W[k * DOUT + n_]);
    }
    uint4 o;
    o.x = (unsigned)v[0] | ((unsigned)v[1] << 16);
    o.y = (unsigned)v[2] | ((unsigned)v[3] << 16);
    o.z = (unsigned)v[4] | ((unsigned)v[5] << 16);
    o.w = (unsigned)v[6] | ((unsigned)v[7] << 16);
    *(uint4*)(out + (size_t)tid * 8) = o;
}

__global__ void prep_kernel(const int* __restrict__ ei, int* __restrict__ counts, int E, int eb,
                            const float* __restrict__ W0, const float* __restrict__ W1,
                            const float* __restrict__ W2,
                            unsigned short* __restrict__ wz0, unsigned short* __restrict__ wz1,
                            unsigned short* __restrict__ wz2) {
    int b = blockIdx.x;
    if (b < eb) {
        int e = b * blockDim.x + threadIdx.x;
        if (e < E) {
            int s = ei[e], d = ei[E + e];
            atomicAdd(&counts[d * NTILE + (s >> TILE_SHIFT)], 1);
        }
    } else {
        int wb = b - eb;                   // 0..19
        if (wb < 8)       wswz_body(W0, wz0, 128, wb * 256 + threadIdx.x);
        else if (wb < 16) wswz_body(W1, wz1, 128, (wb - 8) * 256 + threadIdx.x);
        else {
            int tid = (wb - 16) * 256 + threadIdx.x;
            if (tid < 1024) wswz_body(W2, wz2, 64, tid);
        }
    }
}

// ---------------- scan1: per-block exclusive scan of flat counts[n*8] ----------------
__global__ __launch_bounds__(1024) void scan1_kernel(const int* __restrict__ counts,
                                                     int* __restrict__ excl,
                                                     int* __restrict__ totals, int m) {
    __shared__ int sm[BS_SCAN];
    int tid = threadIdx.x;
    int i = blockIdx.x * BS_SCAN + tid;
    int v = (i < m) ? counts[i] : 0;
    int val = v;
    sm[tid] = val;
    for (int off = 1; off < BS_SCAN; off <<= 1) {
        __syncthreads();
        int t = (tid >= off) ? sm[tid - off] : 0;
        __syncthreads();
        val += t; sm[tid] = val;
    }
    if (i < m) excl[i] = val - v;
    if (tid == BS_SCAN - 1) totals[blockIdx.x] = val;
}

// ---------------- scan2: one block, exclusive scan of totals[nb] (nb <= 1024) ----------------
__global__ __launch_bounds__(1024) void scan2_kernel(int* __restrict__ totals, int nb) {
    __shared__ int sm[1024];
    int tid = threadIdx.x;
    int v = (tid < nb) ? totals[tid] : 0;
    int val = v; sm[tid] = val;
    for (int off = 1; off < 1024; off <<= 1) {
        __syncthreads();
        int t = (tid >= off) ? sm[tid - off] : 0;
        __syncthreads();
        val += t; sm[tid] = val;
    }
    if (tid < nb) totals[tid] = val - v;
}

// ---------------- scan3: add block offset; extract row_ptr (segment starts) ----------------
__global__ __launch_bounds__(1024) void scan3_kernel(int* __restrict__ cursor,
                                                     const int* __restrict__ totals,
                                                     int* __restrict__ row_ptr, int m, int n, int E) {
    int j = blockIdx.x * BS_SCAN + threadIdx.x;
    if (j < m) {
        int rp = cursor[j] + totals[blockIdx.x];
        cursor[j] = rp;
        if ((j & (NTILE - 1)) == 0) row_ptr[j / NTILE] = rp;
    }
    if (j == 0) row_ptr[n] = E;
}

// ---------------- GEMM body (bf16 MFMA) + attention dots, A from global ----------------
template<int DOUT, bool ABF>
__device__ __forceinline__ void gemm_body(
    int bid, const void* __restrict__ Xv, const unsigned short* __restrict__ Wswz,
    const float* __restrict__ avs, const float* __restrict__ avd,
    unsigned* __restrict__ Hout, float* __restrict__ as_out, float* __restrict__ ad_out,
    int n, float* __restrict__ smemw)
{
    constexpr int NT = DOUT / 16;
    int lane = threadIdx.x & 63;
    int w = threadIdx.x >> 6;
    int q = lane >> 4, c = lane & 15;
    int rowbase = bid * 64 + w * 16;
    int arow = rowbase + c;

    f32x4 acc[NT];
#pragma unroll
    for (int t = 0; t < NT; ++t) acc[t] = (f32x4){0.f, 0.f, 0.f, 0.f};

#pragma unroll
    for (int ks = 0; ks < 4; ++ks) {
        bfrag a = (bfrag)0;
        int k0 = ks * 32 + q * 8;
        if (ABF) {
            if (arow < n) a = *(const bfrag*)((const unsigned short*)Xv + (size_t)arow * 128 + k0);
        } else {
            if (arow < n) {
                const float* xp = (const float*)Xv + (size_t)arow * 128 + k0;
                float4 x0 = *(const float4*)xp, x1 = *(const float4*)(xp + 4);
                a[0] = (short)f2bf(x0.x); a[1] = (short)f2bf(x0.y);
                a[2] = (short)f2bf(x0.z); a[3] = (short)f2bf(x0.w);
                a[4] = (short)f2bf(x1.x); a[5] = (short)f2bf(x1.y);
                a[6] = (short)f2bf(x1.z); a[7] = (short)f2bf(x1.w);
            }
        }
#pragma unroll
        for (int t = 0; t < NT; ++t) {
            bfrag b = *(const bfrag*)(Wswz + ((size_t)(ks * NT + t) * 64 + lane) * 8);
            acc[t] = __builtin_amdgcn_mfma_f32_16x16x32_bf16(a, b, acc[t], 0, 0, 0);
        }
    }

    float* sm = smemw + w * (16 * 132);
#pragma unroll
    for (int t = 0; t < NT; ++t)
#pragma unroll
        for (int r = 0; r < 4; ++r)
            sm[(q * 4 + r) * 132 + t * 16 + c] = acc[t][r];
    __builtin_amdgcn_wave_barrier();

    if (DOUT == 128) {
#pragma unroll
        for (int it = 0; it < 4; ++it) {
            int r = it * 4 + q;
            int grow = rowbase + r;
            const float* rp = sm + r * 132 + c * 8;
            float4 xa = *(const float4*)rp, xb4 = *(const float4*)(rp + 4);
            uint4 o;
            o.x = (unsigned)f2bf(xa.x) | ((unsigned)f2bf(xa.y) << 16);
            o.y = (unsigned)f2bf(xa.z) | ((unsigned)f2bf(xa.w) << 16);
            o.z = (unsigned)f2bf(xb4.x) | ((unsigned)f2bf(xb4.y) << 16);
            o.w = (unsigned)f2bf(xb4.z) | ((unsigned)f2bf(xb4.w) << 16);
            if (grow < n) *(uint4*)(Hout + (size_t)grow * 64 + c * 4) = o;
        }
    } else {
#pragma unroll
        for (int it = 0; it < 4; ++it) {
            int r = it * 4 + q;
            int grow = rowbase + r;
            float4 v = *(const float4*)(sm + r * 132 + c * 4);
            uint2 o;
            o.x = (unsigned)f2bf(v.x) | ((unsigned)f2bf(v.y) << 16);
            o.y = (unsigned)f2bf(v.z) | ((unsigned)f2bf(v.w) << 16);
            if (grow < n) *(uint2*)(Hout + (size_t)grow * 32 + c * 2) = o;
        }
    }

    int dr = lane >> 2;
    int c0 = (lane & 3) * (DOUT / 4);
    float s = 0.f, d = 0.f;
#pragma unroll
    for (int j = 0; j < DOUT / 4; j += 4) {
        float4 hv = *(const float4*)(sm + dr * 132 + c0 + j);
        float4 av = *(const float4*)(avs + c0 + j);
        float4 dv = *(const float4*)(avd + c0 + j);
        s += hv.x * av.x + hv.y * av.y + hv.z * av.z + hv.w * av.w;
        d += hv.x * dv.x + hv.y * dv.y + hv.z * dv.z + hv.w * dv.w;
    }
    s += __shfl_down(s, 2); s += __shfl_down(s, 1);
    d += __shfl_down(d, 2); d += __shfl_down(d, 1);
    int grow = rowbase + dr;
    if ((lane & 3) == 0 && grow < n) { as_out[grow] = s; ad_out[grow] = d; }
}

// ---------------- layer-0 GEMM + tile-bucketed CSR scatter in one launch ----------------
__global__ __launch_bounds__(256) void gemm0_scatter_kernel(
    const float* __restrict__ X, const unsigned short* __restrict__ Wswz,
    const float* __restrict__ avs, const float* __restrict__ avd,
    unsigned* __restrict__ Hout, float* __restrict__ as_out, float* __restrict__ ad_out,
    int n, int gemmb,
    const int* __restrict__ ei, int* __restrict__ cursor,
    unsigned short* __restrict__ col, int E)
{
    __shared__ float smem[4 * 16 * 132];
    if (blockIdx.x >= gemmb) {
        int e = (blockIdx.x - gemmb) * blockDim.x + threadIdx.x;
        if (e < E) {
            int s = ei[e], d = ei[E + e];
            int pos = atomicAdd(&cursor[d * NTILE + (s >> TILE_SHIFT)], 1);
            col[pos] = (unsigned short)s;
        }
        return;
    }
    gemm_body<128, false>(blockIdx.x, X, Wswz, avs, avd, Hout, as_out, ad_out, n, smem);
}

// ---------------- fused aggregation + next-layer GEMM (LDS overlaid: 33792 B) ----------------
template<int DOUT>
__global__ __launch_bounds__(256) void agg_gemm_kernel(
    const unsigned* __restrict__ Hb,              // [n,128] bf16 packed, prev h
    const float* __restrict__ as_v, const float* __restrict__ ad_v,
    const float* __restrict__ bias,               // [128] prev bias
    const int* __restrict__ row_ptr, const unsigned short* __restrict__ col,
    const unsigned short* __restrict__ Wswz,      // next W swizzled
    const float* __restrict__ avs, const float* __restrict__ avd,
    unsigned* __restrict__ Hout, float* __restrict__ as_out, float* __restrict__ ad_out, int n)
{
    constexpr int NT = DOUT / 16;
    __shared__ char lbuf[4 * 16 * 132 * 4];       // 33792 B shared by aLDS (17408) then smem
    unsigned short* aLDS = (unsigned short*)lbuf; // 64 rows x 128 bf16, pitch 136
    float* smem = (float*)lbuf;
    int tid = threadIdx.x;
    int gi = tid >> 4, il = tid & 15;

    // ---- phase A: aggregate 64 nodes, SiLU, write bf16 rows to LDS ----
    for (int sub = 0; sub < 4; ++sub) {
        int nl = gi * 4 + sub;
        int node = blockIdx.x * 64 + nl;
        uint4 o = {0u, 0u, 0u, 0u};
        if (node < n) {
            int beg = row_ptr[node], end = row_ptr[node + 1];
            float adv = ad_v[node];
            float c_self = __expf(fminf(lrelu(as_v[node] + adv), 60.f));
            uint4 hs = *(const uint4*)(Hb + (size_t)node * 64 + il * 4);
            float acc[8];
            acc[0] = c_self * bf2f_lo(hs.x); acc[1] = c_self * bf2f_hi(hs.x);
            acc[2] = c_self * bf2f_lo(hs.y); acc[3] = c_self * bf2f_hi(hs.y);
            acc[4] = c_self * bf2f_lo(hs.z); acc[5] = c_self * bf2f_hi(hs.z);
            acc[6] = c_self * bf2f_lo(hs.w); acc[7] = c_self * bf2f_hi(hs.w);
            float dpart = 0.f;
            for (int cb = beg; cb < end; cb += 16) {
                int idx = cb + il;
                int sreg = 0; float creg = 0.f;
                if (idx < end) {
                    sreg = col[idx];
                    creg = __expf(fminf(lrelu(as_v[sreg] + adv), 60.f));
                }
                dpart += creg;
                int cnt = end - cb; if (cnt > 16) cnt = 16;
                for (int k = 0; k < cnt; k += 2) {
                    int s0 = __shfl(sreg, k, 16);     float c0 = __shfl(creg, k, 16);
                    int s1 = __shfl(sreg, k + 1, 16); float c1 = __shfl(creg, k + 1, 16);
                    uint4 h0 = *(const uint4*)(Hb + (size_t)s0 * 64 + il * 4);
                    uint4 h1 = *(const uint4*)(Hb + (size_t)s1 * 64 + il * 4);
                    acc[0] += c0 * bf2f_lo(h0.x); acc[1] += c0 * bf2f_hi(h0.x);
                    acc[2] += c0 * bf2f_lo(h0.y); acc[3] += c0 * bf2f_hi(h0.y);
                    acc[4] += c0 * bf2f_lo(h0.z); acc[5] += c0 * bf2f_hi(h0.z);
                    acc[6] += c0 * bf2f_lo(h0.w); acc[7] += c0 * bf2f_hi(h0.w);
                    acc[0] += c1 * bf2f_lo(h1.x); acc[1] += c1 * bf2f_hi(h1.x);
                    acc[2] += c1 * bf2f_lo(h1.y); acc[3] += c1 * bf2f_hi(h1.y);
                    acc[4] += c1 * bf2f_lo(h1.z); acc[5] += c1 * bf2f_hi(h1.z);
                    acc[6] += c1 * bf2f_lo(h1.w); acc[7] += c1 * bf2f_hi(h1.w);
                }
            }
#pragma unroll
            for (int m = 1; m < 16; m <<= 1) dpart += __shfl_xor(dpart, m, 16);
            float inv = 1.f / (dpart + c_self);
            float4 b0v = *(const float4*)(bias + il * 8);
            float4 b1v = *(const float4*)(bias + il * 8 + 4);
            float v0 = acc[0] * inv + b0v.x, v1 = acc[1] * inv + b0v.y;
            float v2 = acc[2] * inv + b0v.z, v3 = acc[3] * inv + b0v.w;
            float v4 = acc[4] * inv + b1v.x, v5 = acc[5] * inv + b1v.y;
            float v6 = acc[6] * inv + b1v.z, v7 = acc[7] * inv + b1v.w;
            v0 /= (1.f + __expf(-v0)); v1 /= (1.f + __expf(-v1));
            v2 /= (1.f + __expf(-v2)); v3 /= (1.f + __expf(-v3));
            v4 /= (1.f + __expf(-v4)); v5 /= (1.f + __expf(-v5));
            v6 /= (1.f + __expf(-v6)); v7 /= (1.f + __expf(-v7));
            o.x = (unsigned)f2bf(v0) | ((unsigned)f2bf(v1) << 16);
            o.y = (unsigned)f2bf(v2) | ((unsigned)f2bf(v3) << 16);
            o.z = (unsigned)f2bf(v4) | ((unsigned)f2bf(v5) << 16);
            o.w = (unsigned)f2bf(v6) | ((unsigned)f2bf(v7) << 16);
        }
        *(uint4*)(&aLDS[nl * 136 + il * 8]) = o;
    }
    __syncthreads();

    // ---- phase B: GEMM from LDS A ----
    int lane = tid & 63;
    int w = tid >> 6;
    int q = lane >> 4, c = lane & 15;
    int rowbase = blockIdx.x * 64 + w * 16;

    f32x4 acc[NT];
#pragma unroll
    for (int t = 0; t < NT; ++t) acc[t] = (f32x4){0.f, 0.f, 0.f, 0.f};

#pragma unroll
    for (int ks = 0; ks < 4; ++ks) {
        bfrag a = *(const bfrag*)(&aLDS[(w * 16 + c) * 136 + ks * 32 + q * 8]);
#pragma unroll
        for (int t = 0; t < NT; ++t) {
            bfrag b = *(const bfrag*)(Wswz + ((size_t)(ks * NT + t) * 64 + lane) * 8);
            acc[t] = __builtin_amdgcn_mfma_f32_16x16x32_bf16(a, b, acc[t], 0, 0, 0);
        }
    }
    __syncthreads();                      // all aLDS reads done before smem overlay writes

    float* sm = smem + w * (16 * 132);
#pragma unroll
    for (int t = 0; t < NT; ++t)
#pragma unroll
        for (int r = 0; r < 4; ++r)
            sm[(q * 4 + r) * 132 + t * 16 + c] = acc[t][r];
    __builtin_amdgcn_wave_barrier();

    if (DOUT == 128) {
#pragma unroll
        for (int it = 0; it < 4; ++it) {
            int r = it * 4 + q;
            int grow = rowbase + r;
            const float* rp = sm + r * 132 + c * 8;
            float4 xa = *(const float4*)rp, xb4 = *(const float4*)(rp + 4);
            uint4 o;
            o.x = (unsigned)f2bf(xa.x) | ((unsigned)f2bf(xa.y) << 16);
            o.y = (unsigned)f2bf(xa.z) | ((unsigned)f2bf(xa.w) << 16);
            o.z = (unsigned)f2bf(xb4.x) | ((unsigned)f2bf(xb4.y) << 16);
            o.w = (unsigned)f2bf(xb4.z) | ((unsigned)f2bf(xb4.w) << 16);
            if (grow < n) *(uint4*)(Hout + (size_t)grow * 64 + c * 4) = o;
        }
    } else {
#pragma unroll
        for (int it = 0; it < 4; ++it) {
            int r = it * 4 + q;
            int grow = rowbase + r;
            float4 v = *(const float4*)(sm + r * 132 + c * 4);
            uint2 o;
            o.x = (unsigned)f2bf(v.x) | ((unsigned)f2bf(v.y) << 16);
            o.y = (unsigned)f2bf(v.z) | ((unsigned)f2bf(v.w) << 16);
            if (grow < n) *(uint2*)(Hout + (size_t)grow * 32 + c * 2) = o;
        }
    }

    int dr = lane >> 2;
    int c0 = (lane & 3) * (DOUT / 4);
    float s = 0.f, d = 0.f;
#pragma unroll
    for (int j = 0; j < DOUT / 4; j += 4) {
        float4 hv = *(const float4*)(sm + dr * 132 + c0 + j);
        float4 av = *(const float4*)(avs + c0 + j);
        float4 dv = *(const float4*)(avd + c0 + j);
        s += hv.x * av.x + hv.y * av.y + hv.z * av.z + hv.w * av.w;
        d += hv.x * dv.x + hv.y * dv.y + hv.z * dv.z + hv.w * dv.w;
    }
    s += __shfl_down(s, 2); s += __shfl_down(s, 1);
    d += __shfl_down(d, 2); d += __shfl_down(d, 1);
    int grow = rowbase + dr;
    if ((lane & 3) == 0 && grow < n) { as_out[grow] = s; ad_out[grow] = d; }
}

// ---------------- final aggregation: bf16 h [n,64], log_softmax, fp32 out ----------------
__global__ __launch_bounds__(256) void agg64_kernel(
    const unsigned* __restrict__ Hb, const float* __restrict__ as_v,
    const float* __restrict__ ad_v, const float* __restrict__ bias,
    const int* __restrict__ row_ptr, const unsigned short* __restrict__ col,
    float* __restrict__ out, int n)
{
    int tid = threadIdx.x;
    int gi = tid >> 4, il = tid & 15;
    int node = blockIdx.x * 16 + gi;
    if (node >= n) return;
    int beg = row_ptr[node], end = row_ptr[node + 1];
    float adv = ad_v[node];
    float c_self = __expf(fminf(lrelu(as_v[node] + adv), 60.f));

    uint2 hs = *(const uint2*)(Hb + (size_t)node * 32 + il * 2);
    float acc[4];
    acc[0] = c_self * bf2f_lo(hs.x); acc[1] = c_self * bf2f_hi(hs.x);
    acc[2] = c_self * bf2f_lo(hs.y); acc[3] = c_self * bf2f_hi(hs.y);
    float dpart = 0.f;

    for (int cb = beg; cb < end; cb += 16) {
        int idx = cb + il;
        int sreg = 0; float creg = 0.f;
        if (idx < end) {
            sreg = col[idx];
            creg = __expf(fminf(lrelu(as_v[sreg] + adv), 60.f));
        }
        dpart += creg;
        int cnt = end - cb; if (cnt > 16) cnt = 16;
        for (int k = 0; k < cnt; k += 2) {
            int s0 = __shfl(sreg, k, 16);     float c0 = __shfl(creg, k, 16);
            int s1 = __shfl(sreg, k + 1, 16); float c1 = __shfl(creg, k + 1, 16);
            uint2 h0 = *(const uint2*)(Hb + (size_t)s0 * 32 + il * 2);
            uint2 h1 = *(const uint2*)(Hb + (size_t)s1 * 32 + il * 2);
            acc[0] += c0 * bf2f_lo(h0.x); acc[1] += c0 * bf2f_hi(h0.x);
            acc[2] += c0 * bf2f_lo(h0.y); acc[3] += c0 * bf2f_hi(h0.y);
            acc[0] += c1 * bf2f_lo(h1.x); acc[1] += c1 * bf2f_hi(h1.x);
            acc[2] += c1 * bf2f_lo(h1.y); acc[3] += c1 * bf2f_hi(h1.y);
        }
    }

#pragma unroll
    for (int m = 1; m < 16; m <<= 1) dpart += __shfl_xor(dpart, m, 16);
    float inv = 1.f / (dpart + c_self);

    float4 bv = *(const float4*)(bias + il * 4);
    float v0 = acc[0] * inv + bv.x, v1 = acc[1] * inv + bv.y;
    float v2 = acc[2] * inv + bv.z, v3 = acc[3] * inv + bv.w;
    float mx = fmaxf(fmaxf(v0, v1), fmaxf(v2, v3));
#pragma unroll
    for (int m = 1; m < 16; m <<= 1) mx = fmaxf(mx, __shfl_xor(mx, m, 16));
    float sum = __expf(v0 - mx) + __expf(v1 - mx) + __expf(v2 - mx) + __expf(v3 - mx);
#pragma unroll
    for (int m = 1; m < 16; m <<= 1) sum += __shfl_xor(sum, m, 16);
    float ls = mx + logf(sum);
    float4 o = make_float4(v0 - ls, v1 - ls, v2 - ls, v3 - ls);
    *(float4*)(out + (size_t)node * 64 + il * 4) = o;
}

extern "C" void kernel_launch(void* const* d_in, const int* in_sizes, int n_in,
                              void* d_out, int out_size, void* d_ws, size_t ws_size,
                              hipStream_t stream) {
    const float* x   = (const float*)d_in[0];
    const int*   ei  = (const int*)d_in[1];
    const float* W0  = (const float*)d_in[2];
    const float* as0 = (const float*)d_in[3];
    const float* ad0 = (const float*)d_in[4];
    const float* b0  = (const float*)d_in[5];
    const float* W1  = (const float*)d_in[6];
    const float* as1 = (const float*)d_in[7];
    const float* ad1 = (const float*)d_in[8];
    const float* b1  = (const float*)d_in[9];
    const float* W2  = (const float*)d_in[10];
    const float* as2 = (const float*)d_in[11];
    const float* ad2 = (const float*)d_in[12];
    const float* b2  = (const float*)d_in[13];

    int n = in_sizes[0] / 128;
    int E = in_sizes[1] / 2;
    int m = n * NTILE;                     // flat (dst,tile) bucket count

    char* wsp = (char*)d_ws;
    auto alloc = [&](size_t bytes) {
        char* p = wsp;
        wsp += (bytes + 255) & ~(size_t)255;
        return p;
    };
    int*   counts  = (int*)alloc((size_t)m * 4);
    int*   cursor  = (int*)alloc((size_t)m * 4);
    int*   row_ptr = (int*)alloc((size_t)(n + 1) * 4);
    int*   totals  = (int*)alloc(1024 * 4);
    unsigned short* col = (unsigned short*)alloc((size_t)E * 2);
    unsigned short* wz0 = (unsigned short*)alloc(128 * 128 * 2);
    unsigned short* wz1 = (unsigned short*)alloc(128 * 128 * 2);
    unsigned short* wz2 = (unsigned short*)alloc(128 * 64 * 2);
    unsigned* hb0  = (unsigned*)alloc((size_t)n * 64 * 4);   // [n,128] bf16
    unsigned* hb1  = (unsigned*)alloc((size_t)n * 64 * 4);   // [n,128] bf16
    unsigned* hf   = (unsigned*)alloc((size_t)n * 32 * 4);   // [n,64]  bf16
    float*    asbA = (float*)alloc((size_t)n * 4);
    float*    adbA = (float*)alloc((size_t)n * 4);
    float*    asbB = (float*)alloc((size_t)n * 4);
    float*    adbB = (float*)alloc((size_t)n * 4);

    (void)hipMemsetAsync(counts, 0, (size_t)m * 4, stream);
    int eb = (E + 255) / 256;
    int gemmb = (n + 63) / 64;
    int nb1 = (m + BS_SCAN - 1) / BS_SCAN;  // 391 for n=50000; <= 1024 required

    // CSR (dst,tile)-bucket count + W swizzles
    prep_kernel<<<eb + 20, 256, 0, stream>>>(ei, counts, E, eb, W0, W1, W2, wz0, wz1, wz2);
    // 3-phase scan over flat buckets
    scan1_kernel<<<nb1, BS_SCAN, 0, stream>>>(counts, cursor, totals, m);
    scan2_kernel<<<1, 1024, 0, stream>>>(totals, nb1);
    scan3_kernel<<<nb1, BS_SCAN, 0, stream>>>(cursor, totals, row_ptr, m, n, E);
    // layer-0 GEMM + dots, and tile-ordered CSR scatter, in one launch
    gemm0_scatter_kernel<<<gemmb + eb, 256, 0, stream>>>(x, wz0, as0, ad0, hb0, asbA, adbA,
                                                         n, gemmb, ei, cursor, col, E);
    // layer-0 agg + layer-1 GEMM + dots
    agg_gemm_kernel<128><<<gemmb, 256, 0, stream>>>(hb0, asbA, adbA, b0, row_ptr, col,
                                                    wz1, as1, ad1, hb1, asbB, adbB, n);
    // layer-1 agg + layer-2 GEMM + dots
    agg_gemm_kernel<64><<<gemmb, 256, 0, stream>>>(hb1, asbB, adbB, b1, row_ptr, col,
                                                   wz2, as2, ad2, hf, asbA, adbA, n);
    // final agg + log_softmax
    agg64_kernel<<<(n + 15) / 16, 256, 0, stream>>>(hf, asbA, adbA, b2, row_ptr, col,
                                                    (float*)d_out, n);
}

// Round 9
// 294.002 us; speedup vs baseline: 1.4725x; 1.0198x over previous
//
#include <hip/hip_runtime.h>
#include <math.h>

#define NEG_SLOPE 0.2f
constexpr int BS_SCAN = 1024;

typedef __attribute__((ext_vector_type(8))) short bfrag;   // 8 x bf16
typedef __attribute__((ext_vector_type(4))) float f32x4;

__device__ __forceinline__ float lrelu(float x) { return x > 0.f ? x : NEG_SLOPE * x; }

__device__ __forceinline__ unsigned short f2bf(float f) {
    union { float f; unsigned u; } v; v.f = f;
    unsigned r = v.u + 0x7fffu + ((v.u >> 16) & 1u);   // RNE
    return (unsigned short)(r >> 16);
}
__device__ __forceinline__ float bf2f_lo(unsigned p) { union { unsigned u; float f; } v; v.u = p << 16; return v.f; }
__device__ __forceinline__ float bf2f_hi(unsigned p) { union { unsigned u; float f; } v; v.u = p & 0xffff0000u; return v.f; }

// ---------------- prep: per-dst edge count + all 3 W swizzles ----------------
__device__ __forceinline__ void wswz_body(const float* __restrict__ W, unsigned short* __restrict__ out,
                                          int DOUT, int tid) {
    int lane = tid & 63;
    int g = tid >> 6;
    int NT = DOUT >> 4;
    int tile = g % NT, kstep = g / NT;
    int q = lane >> 4, c = lane & 15;
    int n_ = tile * 16 + c;
    unsigned short v[8];
#pragma unroll
    for (int j = 0; j < 8; ++j) {
        int k = kstep * 32 + q * 8 + j;
        v[j] = f2bf(W[k * DOUT + n_]);
    }
    uint4 o;
    o.x = (unsigned)v[0] | ((unsigned)v[1] << 16);
    o.y = (unsigned)v[2] | ((unsigned)v[3] << 16);
    o.z = (unsigned)v[4] | ((unsigned)v[5] << 16);
    o.w = (unsigned)v[6] | ((unsigned)v[7] << 16);
    *(uint4*)(out + (size_t)tid * 8) = o;
}

__global__ void prep_kernel(const int* __restrict__ dst, int* __restrict__ counts, int E, int eb,
                            const float* __restrict__ W0, const float* __restrict__ W1,
                            const float* __restrict__ W2,
                            unsigned short* __restrict__ wz0, unsigned short* __restrict__ wz1,
                            unsigned short* __restrict__ wz2) {
    int b = blockIdx.x;
    if (b < eb) {
        int e = b * blockDim.x + threadIdx.x;
        if (e < E) atomicAdd(&counts[dst[e]], 1);
    } else {
        int wb = b - eb;                   // 0..19
        if (wb < 8)       wswz_body(W0, wz0, 128, wb * 256 + threadIdx.x);
        else if (wb < 16) wswz_body(W1, wz1, 128, (wb - 8) * 256 + threadIdx.x);
        else {
            int tid = (wb - 16) * 256 + threadIdx.x;
            if (tid < 1024) wswz_body(W2, wz2, 64, tid);
        }
    }
}

// ---------------- scan1: per-block exclusive scan of counts[n] ----------------
__global__ __launch_bounds__(1024) void scan1_kernel(const int* __restrict__ counts,
                                                     int* __restrict__ excl,
                                                     int* __restrict__ totals, int n) {
    __shared__ int sm[BS_SCAN];
    int tid = threadIdx.x;
    int i = blockIdx.x * BS_SCAN + tid;
    int v = (i < n) ? counts[i] : 0;
    int val = v;
    sm[tid] = val;
    for (int off = 1; off < BS_SCAN; off <<= 1) {
        __syncthreads();
        int t = (tid >= off) ? sm[tid - off] : 0;
        __syncthreads();
        val += t; sm[tid] = val;
    }
    if (i < n) excl[i] = val - v;
    if (tid == BS_SCAN - 1) totals[blockIdx.x] = val;
}

// ---------------- scan2+3: add block offset (redundant wave-reduce, nb<=64) ----------------
__global__ __launch_bounds__(1024) void scan23_kernel(int* __restrict__ row_ptr,
                                                      const int* __restrict__ totals,
                                                      int* __restrict__ cursor, int n, int E, int nb) {
    __shared__ int s_off;
    int tid = threadIdx.x;
    if (tid < 64) {
        int v = (tid < blockIdx.x && tid < nb) ? totals[tid] : 0;
#pragma unroll
        for (int off = 32; off; off >>= 1) v += __shfl_xor(v, off);
        if (tid == 0) s_off = v;
    }
    __syncthreads();
    int off = s_off;
    int i = blockIdx.x * BS_SCAN + tid;
    if (i < n) {
        int rp = row_ptr[i] + off;
        row_ptr[i] = rp;
        cursor[i] = rp;
    }
    if (i == 0) row_ptr[n] = E;
}

// ---------------- GEMM body (bf16 MFMA) + attention dots ----------------
template<int DOUT, bool ABF>
__device__ __forceinline__ void gemm_body(
    int bid, const void* __restrict__ Xv, const unsigned short* __restrict__ Wswz,
    const float* __restrict__ avs, const float* __restrict__ avd,
    unsigned* __restrict__ Hout, float* __restrict__ as_out, float* __restrict__ ad_out,
    int n, float* __restrict__ smemw)
{
    constexpr int NT = DOUT / 16;
    int lane = threadIdx.x & 63;
    int w = threadIdx.x >> 6;
    int q = lane >> 4, c = lane & 15;
    int rowbase = bid * 64 + w * 16;
    int arow = rowbase + c;

    f32x4 acc[NT];
#pragma unroll
    for (int t = 0; t < NT; ++t) acc[t] = (f32x4){0.f, 0.f, 0.f, 0.f};

#pragma unroll
    for (int ks = 0; ks < 4; ++ks) {
        bfrag a = (bfrag)0;
        int k0 = ks * 32 + q * 8;
        if (ABF) {
            if (arow < n) a = *(const bfrag*)((const unsigned short*)Xv + (size_t)arow * 128 + k0);
        } else {
            if (arow < n) {
                const float* xp = (const float*)Xv + (size_t)arow * 128 + k0;
                float4 x0 = *(const float4*)xp, x1 = *(const float4*)(xp + 4);
                a[0] = (short)f2bf(x0.x); a[1] = (short)f2bf(x0.y);
                a[2] = (short)f2bf(x0.z); a[3] = (short)f2bf(x0.w);
                a[4] = (short)f2bf(x1.x); a[5] = (short)f2bf(x1.y);
                a[6] = (short)f2bf(x1.z); a[7] = (short)f2bf(x1.w);
            }
        }
#pragma unroll
        for (int t = 0; t < NT; ++t) {
            bfrag b = *(const bfrag*)(Wswz + ((size_t)(ks * NT + t) * 64 + lane) * 8);
            acc[t] = __builtin_amdgcn_mfma_f32_16x16x32_bf16(a, b, acc[t], 0, 0, 0);
        }
    }

    float* sm = smemw + w * (16 * 132);
#pragma unroll
    for (int t = 0; t < NT; ++t)
#pragma unroll
        for (int r = 0; r < 4; ++r)
            sm[(q * 4 + r) * 132 + t * 16 + c] = acc[t][r];
    __builtin_amdgcn_wave_barrier();

    if (DOUT == 128) {
#pragma unroll
        for (int it = 0; it < 4; ++it) {
            int r = it * 4 + q;
            int grow = rowbase + r;
            const float* rp = sm + r * 132 + c * 8;
            float4 xa = *(const float4*)rp, xb4 = *(const float4*)(rp + 4);
            uint4 o;
            o.x = (unsigned)f2bf(xa.x) | ((unsigned)f2bf(xa.y) << 16);
            o.y = (unsigned)f2bf(xa.z) | ((unsigned)f2bf(xa.w) << 16);
            o.z = (unsigned)f2bf(xb4.x) | ((unsigned)f2bf(xb4.y) << 16);
            o.w = (unsigned)f2bf(xb4.z) | ((unsigned)f2bf(xb4.w) << 16);
            if (grow < n) *(uint4*)(Hout + (size_t)grow * 64 + c * 4) = o;
        }
    } else {
#pragma unroll
        for (int it = 0; it < 4; ++it) {
            int r = it * 4 + q;
            int grow = rowbase + r;
            float4 v = *(const float4*)(sm + r * 132 + c * 4);
            uint2 o;
            o.x = (unsigned)f2bf(v.x) | ((unsigned)f2bf(v.y) << 16);
            o.y = (unsigned)f2bf(v.z) | ((unsigned)f2bf(v.w) << 16);
            if (grow < n) *(uint2*)(Hout + (size_t)grow * 32 + c * 2) = o;
        }
    }

    int dr = lane >> 2;
    int c0 = (lane & 3) * (DOUT / 4);
    float s = 0.f, d = 0.f;
#pragma unroll
    for (int j = 0; j < DOUT / 4; j += 4) {
        float4 hv = *(const float4*)(sm + dr * 132 + c0 + j);
        float4 av = *(const float4*)(avs + c0 + j);
        float4 dv = *(const float4*)(avd + c0 + j);
        s += hv.x * av.x + hv.y * av.y + hv.z * av.z + hv.w * av.w;
        d += hv.x * dv.x + hv.y * dv.y + hv.z * dv.z + hv.w * dv.w;
    }
    s += __shfl_down(s, 2); s += __shfl_down(s, 1);
    d += __shfl_down(d, 2); d += __shfl_down(d, 1);
    int grow = rowbase + dr;
    if ((lane & 3) == 0 && grow < n) { as_out[grow] = s; ad_out[grow] = d; }
}

// ---------------- layer-0 GEMM + CSR scatter in one launch ----------------
__global__ __launch_bounds__(256) void gemm0_scatter_kernel(
    const float* __restrict__ X, const unsigned short* __restrict__ Wswz,
    const float* __restrict__ avs, const float* __restrict__ avd,
    unsigned* __restrict__ Hout, float* __restrict__ as_out, float* __restrict__ ad_out,
    int n, int gemmb,
    const int* __restrict__ ei, int* __restrict__ cursor,
    unsigned short* __restrict__ col, int E)
{
    __shared__ float smem[4 * 16 * 132];
    if (blockIdx.x >= gemmb) {
        int e = (blockIdx.x - gemmb) * blockDim.x + threadIdx.x;
        if (e < E) {
            int s = ei[e], d = ei[E + e];
            int pos = atomicAdd(&cursor[d], 1);
            col[pos] = (unsigned short)s;
        }
        return;
    }
    gemm_body<128, false>(blockIdx.x, X, Wswz, avs, avd, Hout, as_out, ad_out, n, smem);
}

// ---------------- standalone GEMM layers 1/2 (A = bf16 global) ----------------
template<int DOUT>
__global__ __launch_bounds__(256) void gemm_kernel(
    const unsigned* __restrict__ Xb, const unsigned short* __restrict__ Wswz,
    const float* __restrict__ avs, const float* __restrict__ avd,
    unsigned* __restrict__ Hout, float* __restrict__ as_out, float* __restrict__ ad_out, int n)
{
    __shared__ float smem[4 * 16 * 132];
    gemm_body<DOUT, true>(blockIdx.x, Xb, Wswz, avs, avd, Hout, as_out, ad_out, n, smem);
}

// ---------------- aggregation, 128-wide bf16 h, SiLU, bf16 out (wave/node) ----------------
// 4x16-lane groups, 2x unroll -> 8 gathers in flight; high occupancy (no LDS).
__global__ __launch_bounds__(256) void agg128_kernel(
    const unsigned* __restrict__ Hb, const float* __restrict__ as_v,
    const float* __restrict__ ad_v, const float* __restrict__ bias,
    const int* __restrict__ row_ptr, const unsigned short* __restrict__ col,
    unsigned* __restrict__ outb, int n)
{
    int lane = threadIdx.x & 63;
    int node = blockIdx.x * 4 + (threadIdx.x >> 6);
    if (node >= n) return;
    int g = lane >> 4, i = lane & 15;
    int beg = row_ptr[node], end = row_ptr[node + 1];
    float adv = ad_v[node];
    float c_self = __expf(fminf(lrelu(as_v[node] + adv), 60.f));

    uint4 hs = *(const uint4*)(Hb + (size_t)node * 64 + i * 4);
    float cs0 = (g == 0) ? c_self : 0.f;
    float acc[8];
    acc[0] = cs0 * bf2f_lo(hs.x); acc[1] = cs0 * bf2f_hi(hs.x);
    acc[2] = cs0 * bf2f_lo(hs.y); acc[3] = cs0 * bf2f_hi(hs.y);
    acc[4] = cs0 * bf2f_lo(hs.z); acc[5] = cs0 * bf2f_hi(hs.z);
    acc[6] = cs0 * bf2f_lo(hs.w); acc[7] = cs0 * bf2f_hi(hs.w);
    float dsum = (lane == 0) ? c_self : 0.f;

    for (int cb = beg; cb < end; cb += 64) {
        int idx = cb + lane;
        int sreg = 0; float creg = 0.f;
        if (idx < end) {
            sreg = col[idx];
            creg = __expf(fminf(lrelu(as_v[sreg] + adv), 60.f));
        }
        dsum += creg;
        int cnt = end - cb; if (cnt > 64) cnt = 64;
        for (int k = 0; k < cnt; k += 8) {
            int kk0 = k + g, kk1 = k + g + 4;
            int s0 = __shfl(sreg, kk0);
            int s1 = __shfl(sreg, kk1);
            float c0 = __shfl(creg, kk0);        // lanes >= cnt carry creg=0
            float c1 = __shfl(creg, kk1);
            uint4 h0 = *(const uint4*)(Hb + (size_t)s0 * 64 + i * 4);
            uint4 h1 = *(const uint4*)(Hb + (size_t)s1 * 64 + i * 4);
            acc[0] += c0 * bf2f_lo(h0.x); acc[1] += c0 * bf2f_hi(h0.x);
            acc[2] += c0 * bf2f_lo(h0.y); acc[3] += c0 * bf2f_hi(h0.y);
            acc[4] += c0 * bf2f_lo(h0.z); acc[5] += c0 * bf2f_hi(h0.z);
            acc[6] += c0 * bf2f_lo(h0.w); acc[7] += c0 * bf2f_hi(h0.w);
            acc[0] += c1 * bf2f_lo(h1.x); acc[1] += c1 * bf2f_hi(h1.x);
            acc[2] += c1 * bf2f_lo(h1.y); acc[3] += c1 * bf2f_hi(h1.y);
            acc[4] += c1 * bf2f_lo(h1.z); acc[5] += c1 * bf2f_hi(h1.z);
            acc[6] += c1 * bf2f_lo(h1.w); acc[7] += c1 * bf2f_hi(h1.w);
        }
    }

#pragma unroll
    for (int off = 32; off; off >>= 1) dsum += __shfl_xor(dsum, off);
    float inv = 1.f / dsum;
#pragma unroll
    for (int j = 0; j < 8; ++j) { acc[j] += __shfl_xor(acc[j], 16); acc[j] += __shfl_xor(acc[j], 32); }

    if (g == 0) {
        float4 b0v = *(const float4*)(bias + i * 8);
        float4 b1v = *(const float4*)(bias + i * 8 + 4);
        float v0 = acc[0] * inv + b0v.x, v1 = acc[1] * inv + b0v.y;
        float v2 = acc[2] * inv + b0v.z, v3 = acc[3] * inv + b0v.w;
        float v4 = acc[4] * inv + b1v.x, v5 = acc[5] * inv + b1v.y;
        float v6 = acc[6] * inv + b1v.z, v7 = acc[7] * inv + b1v.w;
        v0 /= (1.f + __expf(-v0)); v1 /= (1.f + __expf(-v1));
        v2 /= (1.f + __expf(-v2)); v3 /= (1.f + __expf(-v3));
        v4 /= (1.f + __expf(-v4)); v5 /= (1.f + __expf(-v5));
        v6 /= (1.f + __expf(-v6)); v7 /= (1.f + __expf(-v7));
        uint4 o;
        o.x = (unsigned)f2bf(v0) | ((unsigned)f2bf(v1) << 16);
        o.y = (unsigned)f2bf(v2) | ((unsigned)f2bf(v3) << 16);
        o.z = (unsigned)f2bf(v4) | ((unsigned)f2bf(v5) << 16);
        o.w = (unsigned)f2bf(v6) | ((unsigned)f2bf(v7) << 16);
        *(uint4*)(outb + (size_t)node * 64 + i * 4) = o;
    }
}

// ---------------- final aggregation: bf16 h [n,64], log_softmax, fp32 out (wave/node) ----------------
__global__ __launch_bounds__(256) void agg64_kernel(
    const unsigned* __restrict__ Hb, const float* __restrict__ as_v,
    const float* __restrict__ ad_v, const float* __restrict__ bias,
    const int* __restrict__ row_ptr, const unsigned short* __restrict__ col,
    float* __restrict__ out, int n)
{
    int lane = threadIdx.x & 63;
    int node = blockIdx.x * 4 + (threadIdx.x >> 6);
    if (node >= n) return;
    int g = lane >> 4, i = lane & 15;
    int beg = row_ptr[node], end = row_ptr[node + 1];
    float adv = ad_v[node];
    float c_self = __expf(fminf(lrelu(as_v[node] + adv), 60.f));

    uint2 hs = *(const uint2*)(Hb + (size_t)node * 32 + i * 2);
    float cs0 = (g == 0) ? c_self : 0.f;
    float acc[4];
    acc[0] = cs0 * bf2f_lo(hs.x); acc[1] = cs0 * bf2f_hi(hs.x);
    acc[2] = cs0 * bf2f_lo(hs.y); acc[3] = cs0 * bf2f_hi(hs.y);
    float dsum = (lane == 0) ? c_self : 0.f;

    for (int cb = beg; cb < end; cb += 64) {
        int idx = cb + lane;
        int sreg = 0; float creg = 0.f;
        if (idx < end) {
            sreg = col[idx];
            creg = __expf(fminf(lrelu(as_v[sreg] + adv), 60.f));
        }
        dsum += creg;
        int cnt = end - cb; if (cnt > 64) cnt = 64;
        for (int k = 0; k < cnt; k += 8) {
            int kk0 = k + g, kk1 = k + g + 4;
            int s0 = __shfl(sreg, kk0);
            int s1 = __shfl(sreg, kk1);
            float c0 = __shfl(creg, kk0);
            float c1 = __shfl(creg, kk1);
            uint2 h0 = *(const uint2*)(Hb + (size_t)s0 * 32 + i * 2);
            uint2 h1 = *(const uint2*)(Hb + (size_t)s1 * 32 + i * 2);
            acc[0] += c0 * bf2f_lo(h0.x); acc[1] += c0 * bf2f_hi(h0.x);
            acc[2] += c0 * bf2f_lo(h0.y); acc[3] += c0 * bf2f_hi(h0.y);
            acc[0] += c1 * bf2f_lo(h1.x); acc[1] += c1 * bf2f_hi(h1.x);
            acc[2] += c1 * bf2f_lo(h1.y); acc[3] += c1 * bf2f_hi(h1.y);
        }
    }

#pragma unroll
    for (int off = 32; off; off >>= 1) dsum += __shfl_xor(dsum, off);
    float inv = 1.f / dsum;
#pragma unroll
    for (int j = 0; j < 4; ++j) { acc[j] += __shfl_xor(acc[j], 16); acc[j] += __shfl_xor(acc[j], 32); }

    float4 bv = *(const float4*)(bias + i * 4);
    float v0 = acc[0] * inv + bv.x, v1 = acc[1] * inv + bv.y;
    float v2 = acc[2] * inv + bv.z, v3 = acc[3] * inv + bv.w;
    float mx = fmaxf(fmaxf(v0, v1), fmaxf(v2, v3));
#pragma unroll
    for (int off = 8; off; off >>= 1) mx = fmaxf(mx, __shfl_xor(mx, off));
    float sum = __expf(v0 - mx) + __expf(v1 - mx) + __expf(v2 - mx) + __expf(v3 - mx);
#pragma unroll
    for (int off = 8; off; off >>= 1) sum += __shfl_xor(sum, off);
    float ls = mx + logf(sum);
    if (g == 0) {
        float4 o = make_float4(v0 - ls, v1 - ls, v2 - ls, v3 - ls);
        *(float4*)(out + (size_t)node * 64 + i * 4) = o;
    }
}

extern "C" void kernel_launch(void* const* d_in, const int* in_sizes, int n_in,
                              void* d_out, int out_size, void* d_ws, size_t ws_size,
                              hipStream_t stream) {
    const float* x   = (const float*)d_in[0];
    const int*   ei  = (const int*)d_in[1];
    const float* W0  = (const float*)d_in[2];
    const float* as0 = (const float*)d_in[3];
    const float* ad0 = (const float*)d_in[4];
    const float* b0  = (const float*)d_in[5];
    const float* W1  = (const float*)d_in[6];
    const float* as1 = (const float*)d_in[7];
    const float* ad1 = (const float*)d_in[8];
    const float* b1  = (const float*)d_in[9];
    const float* W2  = (const float*)d_in[10];
    const float* as2 = (const float*)d_in[11];
    const float* ad2 = (const float*)d_in[12];
    const float* b2  = (const float*)d_in[13];

    int n = in_sizes[0] / 128;
    int E = in_sizes[1] / 2;
    const int* dstv = ei + E;

    char* wsp = (char*)d_ws;
    auto alloc = [&](size_t bytes) {
        char* p = wsp;
        wsp += (bytes + 255) & ~(size_t)255;
        return p;
    };
    int*   counts  = (int*)alloc((size_t)n * 4);
    int*   row_ptr = (int*)alloc((size_t)(n + 1) * 4);
    int*   cursor  = (int*)alloc((size_t)n * 4);
    int*   totals  = (int*)alloc(256 * 4);
    unsigned short* col = (unsigned short*)alloc((size_t)E * 2);
    unsigned short* wz0 = (unsigned short*)alloc(128 * 128 * 2);
    unsigned short* wz1 = (unsigned short*)alloc(128 * 128 * 2);
    unsigned short* wz2 = (unsigned short*)alloc(128 * 64 * 2);
    unsigned* hb0  = (unsigned*)alloc((size_t)n * 64 * 4);   // [n,128] bf16 (pre-agg h)
    unsigned* hb1  = (unsigned*)alloc((size_t)n * 64 * 4);   // [n,128] bf16
    unsigned* hf   = (unsigned*)alloc((size_t)n * 32 * 4);   // [n,64]  bf16
    unsigned* xb   = (unsigned*)alloc((size_t)n * 64 * 4);   // [n,128] bf16 (agg out)
    float*    asbA = (float*)alloc((size_t)n * 4);
    float*    adbA = (float*)alloc((size_t)n * 4);
    float*    asbB = (float*)alloc((size_t)n * 4);
    float*    adbB = (float*)alloc((size_t)n * 4);

    (void)hipMemsetAsync(counts, 0, (size_t)n * 4, stream);
    int eb = (E + 255) / 256;
    int gemmb = (n + 63) / 64;
    int nodeb = (n + 3) / 4;
    int nb = (n + BS_SCAN - 1) / BS_SCAN;   // 49 <= 64

    // CSR count + W swizzles
    prep_kernel<<<eb + 20, 256, 0, stream>>>(dstv, counts, E, eb, W0, W1, W2, wz0, wz1, wz2);
    scan1_kernel<<<nb, BS_SCAN, 0, stream>>>(counts, row_ptr, totals, n);
    scan23_kernel<<<nb, BS_SCAN, 0, stream>>>(row_ptr, totals, cursor, n, E, nb);
    // layer-0 GEMM + dots, and CSR scatter, concurrently
    gemm0_scatter_kernel<<<gemmb + eb, 256, 0, stream>>>(x, wz0, as0, ad0, hb0, asbA, adbA,
                                                         n, gemmb, ei, cursor, col, E);
    // layer 0 agg (high-occupancy standalone)
    agg128_kernel<<<nodeb, 256, 0, stream>>>(hb0, asbA, adbA, b0, row_ptr, col, xb, n);
    // layer 1 GEMM + agg
    gemm_kernel<128><<<gemmb, 256, 0, stream>>>(xb, wz1, as1, ad1, hb1, asbB, adbB, n);
    agg128_kernel<<<nodeb, 256, 0, stream>>>(hb1, asbB, adbB, b1, row_ptr, col, xb, n);
    // layer 2 GEMM + final agg
    gemm_kernel<64><<<gemmb, 256, 0, stream>>>(xb, wz2, as2, ad2, hf, asbA, adbA, n);
    agg64_kernel<<<nodeb, 256, 0, stream>>>(hf, asbA, adbA, b2, row_ptr, col, (float*)d_out, n);
}